// Round 9
// baseline (562.184 us; speedup 1.0000x reference)
//
#include <hip/hip_runtime.h>
#include <cstddef>

// ---------------------------------------------------------------------------
// SegTransformerDecoder — round 21 (consolidation: best-known components).
//  * mfma_conv: round-17/18 exact (BK=32, NT=2, LDS 24KB, ~6 blocks/CU).
//    Round-20's BK=64 REVERTED: halving blocks/CU exposed the vmcnt(0)+
//    barrier drain (m1 80->90us, conflicts 3.7M->5.5M). This 2-phase
//    structure is block-TLP-bound; keep LDS small.
//  * sample_k4: round-16 v2 verbatim (proven 80.5us). r17/18/19 alternatives
//    all neutral-to-negative; pinned by serial gather chain.
//  * First time these two best configs run together.
// ---------------------------------------------------------------------------

#define HW   10000
#define WID  100

typedef __attribute__((ext_vector_type(8))) __bf16 bf16x8;
typedef __attribute__((ext_vector_type(4))) float f32x4;
typedef __attribute__((ext_vector_type(4))) unsigned int uint4v;

#define AS1 __attribute__((address_space(1)))
#define AS3 __attribute__((address_space(3)))

__device__ __forceinline__ float gelu_exact(float x) {
    return 0.5f * x * (1.0f + erff(x * 0.7071067811865475f));
}
__device__ __forceinline__ unsigned short f2bf(float v) {
    unsigned int b = __float_as_uint(v);
    return (unsigned short)((b + 0x7FFFu + ((b >> 16) & 1u)) >> 16);
}
__device__ __forceinline__ float bf2f(short s) {
    return __uint_as_float(((unsigned int)(unsigned short)s) << 16);
}
__device__ __forceinline__ bf16x8 load_frag(const short* p) {
    return __builtin_bit_cast(bf16x8, *(const uint4v*)p);
}

// ---------------------------------------------------------------------------
// bf16 MFMA implicit-GEMM conv, LDS-staged (m97 2-barrier structure), BK=32.
// Tile: 128 oc x (NT*32) pix (NT y-rows x 32 x-cols), 4 waves (2 oc x 2 pix).
// ---------------------------------------------------------------------------
template<int CIN, int KS, int COUT, int EPI, bool ACT, int OPAD, int OPW, int KSPLIT, int NT>
__global__ __launch_bounds__(256)
void mfma_conv(const short* __restrict__ wpk, const short* __restrict__ xcl,
               const float* __restrict__ bias,
               float* __restrict__ outcm, short* __restrict__ outcl)
{
    constexpr int PW = 100 + 2 * (KS / 2);
    constexpr int CHUNK = (KS + KSPLIT - 1) / KSPLIT;
    constexpr int CINB = CIN / 32;          // ic0 steps per (ky,kx)
    constexpr int BBUF = NT * 2048;         // Bs buffer stride in BYTES
    __shared__ short As[8192];              // 2 buffers x [128 oc][32 ic]
    __shared__ short Bs[NT * 2048];         // 2 buffers x [NT*32 pix][32 ic]

    const int t    = threadIdx.x;
    const int lane = t & 63;
    const int wv   = t >> 6;
    const int wr = wv >> 1;
    const int wc = wv & 1;
    const int lq = lane >> 4;
    const int ln = lane & 15;

    const int oc0 = blockIdx.x * 128;
    const int y0  = blockIdx.y * NT;
    const int zb  = blockIdx.z;
    const int bx  = (KSPLIT > 1) ? (zb & 3) : zb;
    const int ks  = (KSPLIT > 1) ? (zb >> 2) : 0;
    const int x0  = bx * 32;
    const int ky_lo = ks * CHUNK;
    const int ky_hi = (ky_lo + CHUNK < KS) ? ky_lo + CHUNK : KS;

    const int srow  = t >> 2;               // 0..63
    const int sslot = (t & 3) * 8;          // shorts (4 x 16B per 64B row)

    const int nsteps = (ky_hi - ky_lo) * KS * CINB;

    f32x4 acc[4][NT];
#pragma unroll
    for (int mt = 0; mt < 4; ++mt)
#pragma unroll
        for (int nt = 0; nt < NT; ++nt)
#pragma unroll
            for (int r = 0; r < 4; ++r) acc[mt][nt][r] = 0.f;

    auto stage = [&](int b, int s) {
        const int ky  = ky_lo + s / (KS * CINB);
        const int rem = s % (KS * CINB);
        const int kx  = rem / CINB;
        const int ic0 = (rem % CINB) * 32;
        const short* wsl = wpk + (size_t)((ky * KS + kx) * COUT + oc0) * CIN + ic0 + sslot;
        const short* xsl = xcl + (size_t)(ky * PW + kx) * CIN + ic0 + sslot;
#pragma unroll
        for (int i = 0; i < 2; ++i) {
            const int row = i * 64 + srow;
            const short* ga = wsl + (size_t)row * CIN;
            __builtin_amdgcn_global_load_lds(
                (const AS1 unsigned int*)ga,
                (AS3 unsigned int*)((AS3 char*)As + b * 8192 + i * 4096 + wv * 1024),
                16, 0, 0);
        }
#pragma unroll
        for (int i = 0; i < NT / 2; ++i) {
            const int np = i * 64 + srow;
            const short* gb = xsl + (size_t)((y0 + (np >> 5)) * PW + x0 + (np & 31)) * CIN;
            __builtin_amdgcn_global_load_lds(
                (const AS1 unsigned int*)gb,
                (AS3 unsigned int*)((AS3 char*)Bs + b * BBUF + i * 4096 + wv * 1024),
                16, 0, 0);
        }
    };

    stage(0, 0);
    __syncthreads();

    int cur = 0;
    for (int s = 0; s < nsteps; ++s) {
        if (s + 1 < nsteps) stage(cur ^ 1, s + 1);

        const short* ab = As + cur * 4096;
        const short* bb = Bs + cur * (NT * 1024);
        bf16x8 a[4], b[NT];
#pragma unroll
        for (int mt = 0; mt < 4; ++mt)
            a[mt] = load_frag(ab + (wr * 64 + mt * 16 + ln) * 32 + lq * 8);
#pragma unroll
        for (int nt = 0; nt < NT; ++nt)
            b[nt] = load_frag(bb + (wc * (NT * 16) + nt * 16 + ln) * 32 + lq * 8);
#pragma unroll
        for (int mt = 0; mt < 4; ++mt)
#pragma unroll
            for (int nt = 0; nt < NT; ++nt)
                acc[mt][nt] = __builtin_amdgcn_mfma_f32_16x16x32_bf16(
                    a[mt], b[nt], acc[mt][nt], 0, 0, 0);

        __syncthreads();
        cur ^= 1;
    }

#pragma unroll
    for (int mt = 0; mt < 4; ++mt) {
        const int ocr = oc0 + wr * 64 + mt * 16 + lq * 4;
        float bb[4];
        if (EPI == 1) {
            const float4 bv = *(const float4*)(bias + ocr);
            bb[0] = bv.x; bb[1] = bv.y; bb[2] = bv.z; bb[3] = bv.w;
        }
#pragma unroll
        for (int nt = 0; nt < NT; ++nt) {
            const int nl = wc * (NT * 16) + nt * 16 + ln;
            const int x = x0 + (nl & 31);
            const int y = y0 + (nl >> 5);
            if (x >= 100) continue;
            if (EPI == 1) {
                float v[4];
#pragma unroll
                for (int r = 0; r < 4; ++r) {
                    float tv = acc[mt][nt][r] + bb[r];
                    if (ACT) tv = gelu_exact(tv);
                    v[r] = tv;
                }
                ushort4 pk;
                pk.x = f2bf(v[0]); pk.y = f2bf(v[1]); pk.z = f2bf(v[2]); pk.w = f2bf(v[3]);
                *(ushort4*)(outcl + ((size_t)(y + OPAD) * OPW + (x + OPAD)) * COUT + ocr) = pk;
            } else {
                const int pix = y * WID + x;
#pragma unroll
                for (int r = 0; r < 4; ++r)
                    outcm[((size_t)ks * COUT + ocr + r) * HW + pix] = acc[mt][nt][r];
            }
        }
    }
}

// fused: out = inorm(bias + res + sum_z slab[z])
template<int NS>
__global__ __launch_bounds__(256)
void red_norm_k(const float* __restrict__ bias, const float* __restrict__ res,
                const float* __restrict__ slab, float* __restrict__ outp)
{
    const int c = blockIdx.x, tid = threadIdx.x;
    const size_t base = (size_t)c * HW;
    const float bc = bias[c];
    float v[40];
    float s1 = 0.f, s2 = 0.f;
#pragma unroll
    for (int k = 0; k < 40; ++k) {
        const int i = tid + k * 256;
        float x = 0.f;
        if (i < HW) {
            x = bc + res[base + i];
#pragma unroll
            for (int z = 0; z < NS; ++z) x += slab[(size_t)z * 1280000 + base + i];
            s1 += x; s2 += x * x;
        }
        v[k] = x;
    }
    __shared__ float r1[256], r2[256];
    r1[tid] = s1; r2[tid] = s2; __syncthreads();
    for (int o = 128; o > 0; o >>= 1) {
        if (tid < o) { r1[tid] += r1[tid + o]; r2[tid] += r2[tid + o]; }
        __syncthreads();
    }
    const float mean = r1[0] * 1e-4f;
    const float var  = fmaxf(r2[0] * 1e-4f - mean * mean, 0.f);
    const float rstd = rsqrtf(var + 1e-5f);
#pragma unroll
    for (int k = 0; k < 40; ++k) {
        const int i = tid + k * 256;
        if (i < HW) outp[base + i] = (v[k] - mean) * rstd;
    }
}

// bev_query fp32 [128][100][100] -> x_cat bf16 channel-last padded(2)
__global__ void pad_cat_x(const float* __restrict__ in, short* __restrict__ out)
{
    const int total = 10816 * 384;
    for (int i = blockIdx.x * blockDim.x + threadIdx.x; i < total; i += gridDim.x * blockDim.x) {
        const int c = i % 384;
        const int p = i / 384;
        const int x = p % 104 - 2;
        const int y = p / 104 - 2;
        const int sc = c & 127;
        float v = 0.f;
        if (x >= 0 && x < 100 && y >= 0 && y < 100) v = in[(size_t)sc * HW + y * WID + x];
        const unsigned short hi = f2bf(v);
        short o;
        if (c >= 128 && c < 256) o = (short)f2bf(v - bf2f((short)hi));
        else                     o = (short)hi;
        out[i] = o;
    }
}

// in_w -> w_cat [(ky*5+kx)*128+oc][384] bf16 (hi/hi/lo)
__global__ void pack_w1_cat(const float* __restrict__ w, short* __restrict__ out)
{
    const int total = 25 * 128 * 384;
    for (int i = blockIdx.x * blockDim.x + threadIdx.x; i < total; i += gridDim.x * blockDim.x) {
        const int c = i % 384;
        int t = i / 384;
        const int oc = t % 128;
        const int s = t / 128;
        const int ky = s / 5, kx = s % 5;
        const int sc = c & 127;
        const float v = w[(((size_t)oc * 128 + sc) * 5 + ky) * 5 + kx];
        const unsigned short hi = f2bf(v);
        out[i] = (c < 256) ? (short)hi : (short)f2bf(v - bf2f((short)hi));
    }
}

template<int C, int PAD>
__global__ void pad_cl_cast(const float* __restrict__ in, short* __restrict__ out)
{
    constexpr int PW = 100 + 2 * PAD;
    const int total = PW * PW * C;
    for (int i = blockIdx.x * blockDim.x + threadIdx.x; i < total; i += gridDim.x * blockDim.x) {
        const int c = i % C;
        const int p = i / C;
        const int x = p % PW - PAD;
        const int y = p / PW - PAD;
        float v = 0.f;
        if (x >= 0 && x < 100 && y >= 0 && y < 100) v = in[(size_t)c * HW + y * WID + x];
        out[i] = (short)f2bf(v);
    }
}

__global__ void pack_all_bf16(const float* __restrict__ w1, const float* __restrict__ w2,
                              const float* __restrict__ w3, const float* __restrict__ w4,
                              short* __restrict__ out)
{
    const int E0 = 1179648, E1 = E0 + 262144, E2 = E1 + 589824, E3 = E2 + 409600;
    for (int i = blockIdx.x * blockDim.x + threadIdx.x; i < E3; i += gridDim.x * blockDim.x) {
        const float* w; int OC, CI, KS, j;
        if (i < E0)      { w = w1; OC = 512; CI = 256; KS = 3; j = i; }
        else if (i < E1) { w = w2; OC = 512; CI = 512; KS = 1; j = i - E0; }
        else if (i < E2) { w = w3; OC = 128; CI = 512; KS = 3; j = i - E1; }
        else             { w = w4; OC = 128; CI = 128; KS = 5; j = i - E2; }
        const int ic = j % CI;
        int t = j / CI;
        const int oc = t % OC;
        const int s = t / OC;
        const int ky = s / KS, kx = s % KS;
        out[i] = (short)f2bf(w[(((size_t)oc * CI + ic) * KS + ky) * KS + kx]);
    }
}

// feature transposes -> bf16 channel-last, concatenated
__global__ void transpose_all(const float* __restrict__ f0, const float* __restrict__ f1,
                              const float* __restrict__ f2, const float* __restrict__ f3,
                              short* __restrict__ out)
{
    const int O1 = 2230272, O2 = O1 + 557568, O3 = O2 + 139392, O4 = O3 + 34848;
    for (int i = blockIdx.x * blockDim.x + threadIdx.x; i < O4; i += gridDim.x * blockDim.x) {
        const float* f; int Hl, Wl, j;
        if (i < O1)      { f = f0; Hl = 32; Wl = 88; j = i; }
        else if (i < O2) { f = f1; Hl = 16; Wl = 44; j = i - O1; }
        else if (i < O3) { f = f2; Hl = 8;  Wl = 22; j = i - O2; }
        else             { f = f3; Hl = 4;  Wl = 11; j = i - O3; }
        const int c = j % 132;
        int t = j / 132;
        const int x = t % Wl; t /= Wl;
        const int y = t % Hl; t /= Hl;
        const int n = t;
        out[i] = (short)f2bf(f[(((size_t)n * 132 + c) * Hl + y) * Wl + x]);
    }
}

// offsw + projection compaction fused (unchanged)
__global__ __launch_bounds__(64)
void offsw_proj(const float* __restrict__ qn, const float* __restrict__ bev_pos,
                const float* __restrict__ off_w, const float* __restrict__ off_b,
                const float* __restrict__ sw_w, const float* __restrict__ sw_b,
                const float* __restrict__ l2i,
                float* __restrict__ refp, float* __restrict__ swts,
                float2* __restrict__ recs, int* __restrict__ recn, int* __restrict__ cnts)
{
    const int pix = blockIdx.x;
    const int tid = threadIdx.x;
    __shared__ float qv[128];
    __shared__ float swraw[32];
    __shared__ float rp[24];
    qv[tid]      = qn[(size_t)tid * HW + pix];
    qv[tid + 64] = qn[(size_t)(tid + 64) * HW + pix];
    __syncthreads();

    if (tid < 24) {
        float acc = off_b[tid];
        for (int c = 0; c < 128; ++c) acc = fmaf(qv[c], off_w[tid * 128 + c], acc);
        const float s = 1.0f / (1.0f + expf(-acc));
        const int coord = tid % 3;
        const float rng = (coord < 2) ? 0.250001f : 4.000001f;
        const float v = s * rng * 2.0f - rng;
        const float lo[3]   = {-50.f, -50.f, -5.f};
        const float span[3] = {100.f, 100.f, 8.f};
        const float rv = bev_pos[pix * 3 + coord] * span[coord] + lo[coord] + v;
        refp[pix * 24 + tid] = rv;
        rp[tid] = rv;
    } else if (tid >= 32) {
        const int j = tid - 32;
        float acc = sw_b[j];
        for (int c = 0; c < 128; ++c) acc = fmaf(qv[c], sw_w[j * 128 + c], acc);
        swraw[j] = acc;
    }
    __syncthreads();
    if (tid < 8) {
        float m = -1e30f;
#pragma unroll
        for (int l = 0; l < 4; ++l) m = fmaxf(m, swraw[tid * 4 + l]);
        float e[4], sum = 0.f;
#pragma unroll
        for (int l = 0; l < 4; ++l) { e[l] = expf(swraw[tid * 4 + l] - m); sum += e[l]; }
        const float inv = 1.0f / sum;
#pragma unroll
        for (int l = 0; l < 4; ++l) swts[pix * 32 + tid * 4 + l] = e[l] * inv;
    }

    bool keep = false;
    float gx = -2.f, gy = -2.f;
    int p = 0, n = 0;
    if (tid < 48) {
        p = tid / 6;
        n = tid - p * 6;
        const float X = rp[p * 3 + 0], Y = rp[p * 3 + 1], Z = rp[p * 3 + 2];
        const float* m = l2i + n * 16;
        const float cx = m[0] * X + m[1] * Y + m[2]  * Z + m[3];
        const float cy = m[4] * X + m[5] * Y + m[6]  * Z + m[7];
        const float cz = m[8] * X + m[9] * Y + m[10] * Z + m[11];
        const bool valid = cz > 1e-5f;
        const float zz = fmaxf(cz, 1e-5f);
        gx = valid ? (cx / zz) * (2.0f / 704.0f) - 1.0f : -2.0f;
        gy = valid ? (cy / zz) * (2.0f / 256.0f) - 1.0f : -2.0f;
        keep = (gx > -1.092f) && (gx < 1.092f) && (gy > -1.26f) && (gy < 1.26f);
    }
    const unsigned long long bm = __ballot(keep);
    if (keep) {
        const unsigned long long gmask = 0x3Full << (p * 6);
        const int slot = __popcll(bm & ((1ull << tid) - 1ull) & gmask);
        recs[(size_t)pix * 48 + p * 6 + slot] = make_float2(gx, gy);
        recn[(size_t)pix * 48 + p * 6 + slot] = n;
    }
    if (tid < 48 && (tid % 6) == 0) {
        const unsigned long long gmask = 0x3Full << (p * 6);
        cnts[pix * 8 + p] = __popcll(bm & gmask);
    }
}

// ---------------------------------------------------------------------------
// sample_k4 — round-16 v2 verbatim (proven 80.5us): no divergent tail,
// 1-deep register prefetch over r, weights in registers.
// ---------------------------------------------------------------------------
__global__ __launch_bounds__(64)
void sample_k4(const float* __restrict__ refp, const float* __restrict__ swts,
               const float2* __restrict__ recs, const int* __restrict__ recn,
               const int* __restrict__ cnts,
               const short* __restrict__ fb0,   // concatenated bf16 feats
               short* __restrict__ sfo)
{
    const int pix = blockIdx.x;
    const int tid = threadIdx.x;                   // 64
    const int c0  = tid * 2;                       // channels c0, c0+1
    __shared__ float rp[24], sw[32], tail[32];
    __shared__ float2 rec[48];
    __shared__ int rn[48];
    __shared__ int cnt[8];
    __shared__ int4   toff[192];
    __shared__ float4 twt[192];
    if (tid < 24) rp[tid] = refp[pix * 24 + tid];
    if (tid < 32) sw[tid] = swts[pix * 32 + tid];
    if (tid < 48) { rec[tid] = recs[(size_t)pix * 48 + tid]; rn[tid] = recn[(size_t)pix * 48 + tid]; }
    if (tid < 8)  cnt[tid] = cnts[pix * 8 + tid];
    __syncthreads();

    const int HL[4] = {32, 16, 8, 4};
    const int WL[4] = {88, 44, 22, 11};
    const int LB[4] = {0, 2230272, 2787840, 2927232};   // level bases (shorts)

    for (int e = tid; e < 192; e += 64) {
        const int p  = e / 24;
        const int rl = e - p * 24;
        const int r  = rl >> 2;
        const int l  = rl & 3;
        int4 off = make_int4(0, 0, 0, 0);
        float4 wt = make_float4(0.f, 0.f, 0.f, 0.f);
        if (r < cnt[p]) {
            const float gx = rec[p * 6 + r].x;
            const float gy = rec[p * 6 + r].y;
            const int   n  = rn[p * 6 + r];
            const float wl = sw[p * 4 + l];
            const int Hl = HL[l], Wl = WL[l];
            const float fx = (gx + 1.0f) * 0.5f * (float)Wl - 0.5f;
            const float fy = (gy + 1.0f) * 0.5f * (float)Hl - 0.5f;
            if (fx >= -1.0f && fx < (float)Wl && fy >= -1.0f && fy < (float)Hl) {
                const float x0f = floorf(fx), y0f = floorf(fy);
                const int x0 = (int)x0f, y0 = (int)y0f;
                const int x1 = x0 + 1, y1 = y0 + 1;
                const float wx1 = fx - x0f, wy1 = fy - y0f;
                const float wx0 = 1.0f - wx1, wy0 = 1.0f - wy1;
                const bool okx0 = (x0 >= 0), okx1 = (x1 < Wl);
                const bool oky0 = (y0 >= 0), oky1 = (y1 < Hl);
                const int xc0 = okx0 ? x0 : 0, xc1 = okx1 ? x1 : Wl - 1;
                const int yc0 = oky0 ? y0 : 0, yc1 = oky1 ? y1 : Hl - 1;
                const int base = LB[l] + n * Hl * Wl * 132;
                off.x = base + (yc0 * Wl + xc0) * 132;
                off.y = base + (yc0 * Wl + xc1) * 132;
                off.z = base + (yc1 * Wl + xc0) * 132;
                off.w = base + (yc1 * Wl + xc1) * 132;
                wt.x = (okx0 && oky0) ? wx0 * wy0 * wl : 0.f;
                wt.y = (okx1 && oky0) ? wx1 * wy0 * wl : 0.f;
                wt.z = (okx0 && oky1) ? wx0 * wy1 * wl : 0.f;
                wt.w = (okx1 && oky1) ? wx1 * wy1 * wl : 0.f;
            }
        }
        toff[e] = off;
        twt[e]  = wt;
    }
    __syncthreads();

    // load one r-batch (16 taps + 16 weights) into static registers
#define LOADB(L, W, P, R)                                                        \
    do {                                                                         \
        const int eb_ = (P) * 24 + (R) * 4;                                      \
        _Pragma("unroll")                                                        \
        for (int l = 0; l < 4; ++l) {                                            \
            const int4 offv_ = toff[eb_ + l];                                    \
            W[l] = twt[eb_ + l];                                                 \
            const int ox_ = __builtin_amdgcn_readfirstlane(offv_.x);             \
            const int oy_ = __builtin_amdgcn_readfirstlane(offv_.y);             \
            const int oz_ = __builtin_amdgcn_readfirstlane(offv_.z);             \
            const int ow_ = __builtin_amdgcn_readfirstlane(offv_.w);             \
            L[l * 4 + 0] = *(const unsigned int*)(fb0 + ox_ + c0);               \
            L[l * 4 + 1] = *(const unsigned int*)(fb0 + oy_ + c0);               \
            L[l * 4 + 2] = *(const unsigned int*)(fb0 + oz_ + c0);               \
            L[l * 4 + 3] = *(const unsigned int*)(fb0 + ow_ + c0);               \
        }                                                                        \
    } while (0)

#define FMAB(L, W)                                                               \
    do {                                                                         \
        _Pragma("unroll")                                                        \
        for (int l = 0; l < 4; ++l) {                                            \
            a0.x = fmaf(__uint_as_float(L[l * 4 + 0] << 16),          W[l].x, a0.x); \
            a0.y = fmaf(__uint_as_float(L[l * 4 + 0] & 0xFFFF0000u),  W[l].x, a0.y); \
            a1.x = fmaf(__uint_as_float(L[l * 4 + 1] << 16),          W[l].y, a1.x); \
            a1.y = fmaf(__uint_as_float(L[l * 4 + 1] & 0xFFFF0000u),  W[l].y, a1.y); \
            a2.x = fmaf(__uint_as_float(L[l * 4 + 2] << 16),          W[l].z, a2.x); \
            a2.y = fmaf(__uint_as_float(L[l * 4 + 2] & 0xFFFF0000u),  W[l].z, a2.y); \
            a3.x = fmaf(__uint_as_float(L[l * 4 + 3] << 16),          W[l].w, a3.x); \
            a3.y = fmaf(__uint_as_float(L[l * 4 + 3] & 0xFFFF0000u),  W[l].w, a3.y); \
        }                                                                        \
    } while (0)

    float2 acc[8];
#pragma unroll
    for (int p = 0; p < 8; ++p) {
        float2 a0 = {0.f, 0.f}, a1 = {0.f, 0.f}, a2 = {0.f, 0.f}, a3 = {0.f, 0.f};
        const int c = cnt[p];
        unsigned int LA[16]; float4 WA[4];
        if (c > 0) LOADB(LA, WA, p, 0);
        int r = 0;
        while (r < c) {
            unsigned int LB2[16]; float4 WB[4];
            if (r + 1 < c) LOADB(LB2, WB, p, r + 1);
            FMAB(LA, WA);
            ++r;
            if (r >= c) break;
            if (r + 1 < c) LOADB(LA, WA, p, r + 1);
            FMAB(LB2, WB);
            ++r;
        }
        acc[p].x = (a0.x + a1.x) + (a2.x + a3.x);
        acc[p].y = (a0.y + a1.y) + (a2.y + a3.y);
    }
#undef LOADB
#undef FMAB

    // tail channels 128..130 (pos3d): tap-parallel, 8 lanes per point
    {
        const int p   = tid >> 3;
        const int sub = tid & 7;
        const int c   = cnt[p];
        const int nslots = c * 16;              // (4 levels * c rows) entries x 4 taps
        float t0 = 0.f, t1 = 0.f, t2 = 0.f;
        for (int s = sub; s < nslots; s += 8) {
            const int e  = p * 24 + (s >> 2);
            const int tp = s & 3;
            const int4   offv = toff[e];
            const float4 wtv  = twt[e];
            const int   off = (tp == 0) ? offv.x : (tp == 1) ? offv.y : (tp == 2) ? offv.z : offv.w;
            const float w   = (tp == 0) ? wtv.x  : (tp == 1) ? wtv.y  : (tp == 2) ? wtv.z  : wtv.w;
            const uint2 u = *(const uint2*)(fb0 + off + 128);   // ch128..131 (8B aligned)
            t0 = fmaf(__uint_as_float(u.x << 16),         w, t0);
            t1 = fmaf(__uint_as_float(u.x & 0xFFFF0000u), w, t1);
            t2 = fmaf(__uint_as_float(u.y << 16),         w, t2);
        }
#pragma unroll
        for (int o = 4; o > 0; o >>= 1) {
            t0 += __shfl_down(t0, o, 8);
            t1 += __shfl_down(t1, o, 8);
            t2 += __shfl_down(t2, o, 8);
        }
        if (sub == 0) {
            tail[p * 4 + 0] = t0;
            tail[p * 4 + 1] = t1;
            tail[p * 4 + 2] = t2;
        }
    }
    __syncthreads();

    float2 sf1 = {0.f, 0.f}, sf2 = {0.f, 0.f};
#pragma unroll
    for (int p = 0; p < 8; ++p) {
        const float dx = rp[p * 3]     - tail[p * 4 + 0];
        const float dy = rp[p * 3 + 1] - tail[p * 4 + 1];
        const float dz = rp[p * 3 + 2] - tail[p * 4 + 2];
        const float wgt = expf(-0.1f * (dx * dx + dy * dy + dz * dz));
        sf1.x += acc[p].x;  sf1.y += acc[p].y;
        sf2.x += acc[p].x * wgt;  sf2.y += acc[p].y * wgt;
    }
    const int y = pix / WID, x = pix % WID;
    const size_t po = ((size_t)(y + 1) * 102 + (x + 1)) * 256;
    ushort2 p1; p1.x = f2bf(sf1.x); p1.y = f2bf(sf1.y);
    ushort2 p2; p2.x = f2bf(sf2.x); p2.y = f2bf(sf2.y);
    *(ushort2*)(sfo + po + c0)       = p1;
    *(ushort2*)(sfo + po + 128 + c0) = p2;
}

// ---------------------------------------------------------------------------

extern "C" void kernel_launch(void* const* d_in, const int* in_sizes, int n_in,
                              void* d_out, int out_size, void* d_ws, size_t ws_size,
                              hipStream_t stream)
{
    const float* bev_query = (const float*)d_in[0];
    const float* bev_pos   = (const float*)d_in[1];
    const float* l2i       = (const float*)d_in[2];
    const float* feat0     = (const float*)d_in[3];
    const float* feat1     = (const float*)d_in[4];
    const float* feat2     = (const float*)d_in[5];
    const float* feat3     = (const float*)d_in[6];
    const float* in_w      = (const float*)d_in[7];
    const float* in_b      = (const float*)d_in[8];
    const float* off_w     = (const float*)d_in[9];
    const float* off_b     = (const float*)d_in[10];
    const float* sw_w      = (const float*)d_in[11];
    const float* sw_b      = (const float*)d_in[12];
    const float* mid_w1    = (const float*)d_in[13];
    const float* mid_b1    = (const float*)d_in[14];
    const float* mid_w2    = (const float*)d_in[15];
    const float* mid_b2    = (const float*)d_in[16];
    const float* mid_w3    = (const float*)d_in[17];
    const float* mid_b3    = (const float*)d_in[18];
    const float* out_w     = (const float*)d_in[19];
    const float* out_b     = (const float*)d_in[20];
    float* out = (float*)d_out;

    // ---- workspace layout (lifetime-aliased) ----
    float* ws    = (float*)d_ws;
    float* qn    = ws;                       // 1,280,000
    float* refp  = qn + 1280000;             //   240,000
    float* swts  = refp + 240000;            //   320,000
    float* E     = swts + 320000;            // 6,400,000 (slab5 | fTb+recs | m1_cl | slab3/5)
    float* F     = E + 6400000;              // 1,800,000 (xcat+wcat | sf_cl | q2pad)
    float* H     = F + 1800000;              // 2,700,000 (wcat tail | m2_cl)
    short* wp_all= (short*)(H + 2700000);    // 2,441,216 sh

    float*  slab  = E;                       // conv1/conv4: 5 slabs; conv3: 3 slabs
    short*  fT0   = (short*)E;               // 2,962,080 shorts (bf16 feats, concatenated)
    float2* recs  = (float2*)(E + 1600000);  // 480,000 f2
    int*    recn  = (int*)(E + 2560000);     // 480,000
    int*    cnts  = (int*)(E + 3040000);     //  80,000
    short*  m1_cl = (short*)E;               // 5,120,000 sh [100][100][512]
    short*  xcat  = (short*)F;               // 4,153,344 sh [104][104][384] hi/lo/hi
    short*  wcat  = (short*)(F + 2100000);   // 1,228,800 sh (spills into H; dead by m2)
    short*  sf_cl = (short*)F;               // 2,663,424 sh [102][102][256]
    short*  q2pad = (short*)F;               // 1,384,448 sh [104][104][128]
    short*  m2_cl = (short*)H;               // 5,326,848 sh [102][102][512]
    short*  wp_m1 = wp_all;                  // 1,179,648
    short*  wp_m2 = wp_m1 + 1179648;         //   262,144
    short*  wp_m3 = wp_m2 + 262144;          //   589,824
    short*  wp_out= wp_m3 + 589824;          //   409,600

    const dim3 blk(256);

    // ---- weight packing ----
    hipLaunchKernelGGL(pack_w1_cat, dim3(1200), blk, 0, stream, in_w, wcat);
    hipLaunchKernelGGL(pack_all_bf16, dim3(9536), blk, 0, stream,
                       mid_w1, mid_w2, mid_w3, out_w, wp_all);

    // ---- 1. q1 slabs = conv5x5 split-bf16 MFMA, then qn = inorm fused ----
    hipLaunchKernelGGL(pad_cat_x, dim3(4056), blk, 0, stream, bev_query, xcat);
    hipLaunchKernelGGL((mfma_conv<384, 5, 128, 2, false, 0, 0, 5, 2>), dim3(1, 50, 20), blk, 0, stream,
                       wcat, xcat, in_b, slab, nullptr);
    hipLaunchKernelGGL(red_norm_k<5>, dim3(128), blk, 0, stream, in_b, bev_query, slab, qn);

    // ---- 2. ref points + softmax weights + projection compaction ----
    hipLaunchKernelGGL(offsw_proj, dim3(HW), dim3(64), 0, stream,
                       qn, bev_pos, off_w, off_b, sw_w, sw_b, l2i,
                       refp, swts, recs, recn, cnts);

    // ---- 3. feature transposes -> bf16 (slab5 dead) ----
    hipLaunchKernelGGL(transpose_all, dim3(11571), blk, 0, stream,
                       feat0, feat1, feat2, feat3, fT0);

    // ---- 4. sampling -> sf_cl bf16 padded(1) (xcat/wcat dead) ----
    hipMemsetAsync(sf_cl, 0, (size_t)2663424 * 2, stream);
    hipLaunchKernelGGL(sample_k4, dim3(HW), dim3(64), 0, stream,
                       refp, swts, recs, recn, cnts, fT0, sf_cl);

    // ---- 5. m1 = gelu(conv3x3 256->512), NT=2: 800 blocks ----
    hipLaunchKernelGGL((mfma_conv<256, 3, 512, 1, true, 0, 100, 1, 2>), dim3(4, 50, 4), blk, 0, stream,
                       wp_m1, sf_cl, mid_b1, nullptr, m1_cl);
    // ---- 6. m2 = gelu(conv1x1 512->512) -> padded(1), NT=2: 800 blocks ----
    hipMemsetAsync(m2_cl, 0, (size_t)5326848 * 2, stream);
    hipLaunchKernelGGL((mfma_conv<512, 1, 512, 1, true, 1, 102, 1, 2>), dim3(4, 50, 4), blk, 0, stream,
                       wp_m2, m1_cl, mid_b2, nullptr, m2_cl);
    // ---- 7. q2 = inorm(qn + conv3x3 512->128), NT=2: 600 blocks ----
    hipLaunchKernelGGL((mfma_conv<512, 3, 128, 2, false, 0, 0, 3, 2>), dim3(1, 50, 12), blk, 0, stream,
                       wp_m3, m2_cl, mid_b3, slab, nullptr);
    hipLaunchKernelGGL(red_norm_k<3>, dim3(128), blk, 0, stream, mid_b3, qn, slab, qn);
    // ---- 8. q3 = inorm(qn + conv5x5 bf16), NT=2 + KSPLIT=5: 1000 blocks ----
    hipLaunchKernelGGL((pad_cl_cast<128, 2>), dim3(5411), blk, 0, stream, qn, q2pad);
    hipLaunchKernelGGL((mfma_conv<128, 5, 128, 2, false, 0, 0, 5, 2>), dim3(1, 50, 20), blk, 0, stream,
                       wp_out, q2pad, out_b, slab, nullptr);
    hipLaunchKernelGGL(red_norm_k<5>, dim3(128), blk, 0, stream, out_b, qn, slab, out);
}

// Round 10
// 511.286 us; speedup vs baseline: 1.0995x; 1.0995x over previous
//
#include <hip/hip_runtime.h>
#include <cstddef>

// ---------------------------------------------------------------------------
// SegTransformerDecoder — round 22 (structural work elimination).
//  * Session noise forensics: identical sampler binary measured 80.5us (r16)
//    vs 88-91us (r21); totals 520-562 for equivalent configs. Cross-session
//    deltas <10% are noise — only monotone work reductions from here.
//  * Both full-buffer memsets (16MB/launch) replaced by zero_borders:
//    only the 404-px pad rings of sf_cl/m2_cl need zeroing (interiors are
//    fully overwritten by sample_k4 / m2-conv). 0.62MB, 1 dispatch vs 2.
//  * pack_w1_cat fused into pack_all_bf16 (5th segment): -1 dispatch.
//  * Convs (BK=32, NT=2, LDS 24KB) and sampler (r16 v2) unchanged from r21.
// ---------------------------------------------------------------------------

#define HW   10000
#define WID  100

typedef __attribute__((ext_vector_type(8))) __bf16 bf16x8;
typedef __attribute__((ext_vector_type(4))) float f32x4;
typedef __attribute__((ext_vector_type(4))) unsigned int uint4v;

#define AS1 __attribute__((address_space(1)))
#define AS3 __attribute__((address_space(3)))

__device__ __forceinline__ float gelu_exact(float x) {
    return 0.5f * x * (1.0f + erff(x * 0.7071067811865475f));
}
__device__ __forceinline__ unsigned short f2bf(float v) {
    unsigned int b = __float_as_uint(v);
    return (unsigned short)((b + 0x7FFFu + ((b >> 16) & 1u)) >> 16);
}
__device__ __forceinline__ float bf2f(short s) {
    return __uint_as_float(((unsigned int)(unsigned short)s) << 16);
}
__device__ __forceinline__ bf16x8 load_frag(const short* p) {
    return __builtin_bit_cast(bf16x8, *(const uint4v*)p);
}

// ---------------------------------------------------------------------------
// bf16 MFMA implicit-GEMM conv, LDS-staged (m97 2-barrier structure), BK=32.
// Tile: 128 oc x (NT*32) pix (NT y-rows x 32 x-cols), 4 waves (2 oc x 2 pix).
// ---------------------------------------------------------------------------
template<int CIN, int KS, int COUT, int EPI, bool ACT, int OPAD, int OPW, int KSPLIT, int NT>
__global__ __launch_bounds__(256)
void mfma_conv(const short* __restrict__ wpk, const short* __restrict__ xcl,
               const float* __restrict__ bias,
               float* __restrict__ outcm, short* __restrict__ outcl)
{
    constexpr int PW = 100 + 2 * (KS / 2);
    constexpr int CHUNK = (KS + KSPLIT - 1) / KSPLIT;
    constexpr int CINB = CIN / 32;          // ic0 steps per (ky,kx)
    constexpr int BBUF = NT * 2048;         // Bs buffer stride in BYTES
    __shared__ short As[8192];              // 2 buffers x [128 oc][32 ic]
    __shared__ short Bs[NT * 2048];         // 2 buffers x [NT*32 pix][32 ic]

    const int t    = threadIdx.x;
    const int lane = t & 63;
    const int wv   = t >> 6;
    const int wr = wv >> 1;
    const int wc = wv & 1;
    const int lq = lane >> 4;
    const int ln = lane & 15;

    const int oc0 = blockIdx.x * 128;
    const int y0  = blockIdx.y * NT;
    const int zb  = blockIdx.z;
    const int bx  = (KSPLIT > 1) ? (zb & 3) : zb;
    const int ks  = (KSPLIT > 1) ? (zb >> 2) : 0;
    const int x0  = bx * 32;
    const int ky_lo = ks * CHUNK;
    const int ky_hi = (ky_lo + CHUNK < KS) ? ky_lo + CHUNK : KS;

    const int srow  = t >> 2;               // 0..63
    const int sslot = (t & 3) * 8;          // shorts (4 x 16B per 64B row)

    const int nsteps = (ky_hi - ky_lo) * KS * CINB;

    f32x4 acc[4][NT];
#pragma unroll
    for (int mt = 0; mt < 4; ++mt)
#pragma unroll
        for (int nt = 0; nt < NT; ++nt)
#pragma unroll
            for (int r = 0; r < 4; ++r) acc[mt][nt][r] = 0.f;

    auto stage = [&](int b, int s) {
        const int ky  = ky_lo + s / (KS * CINB);
        const int rem = s % (KS * CINB);
        const int kx  = rem / CINB;
        const int ic0 = (rem % CINB) * 32;
        const short* wsl = wpk + (size_t)((ky * KS + kx) * COUT + oc0) * CIN + ic0 + sslot;
        const short* xsl = xcl + (size_t)(ky * PW + kx) * CIN + ic0 + sslot;
#pragma unroll
        for (int i = 0; i < 2; ++i) {
            const int row = i * 64 + srow;
            const short* ga = wsl + (size_t)row * CIN;
            __builtin_amdgcn_global_load_lds(
                (const AS1 unsigned int*)ga,
                (AS3 unsigned int*)((AS3 char*)As + b * 8192 + i * 4096 + wv * 1024),
                16, 0, 0);
        }
#pragma unroll
        for (int i = 0; i < NT / 2; ++i) {
            const int np = i * 64 + srow;
            const short* gb = xsl + (size_t)((y0 + (np >> 5)) * PW + x0 + (np & 31)) * CIN;
            __builtin_amdgcn_global_load_lds(
                (const AS1 unsigned int*)gb,
                (AS3 unsigned int*)((AS3 char*)Bs + b * BBUF + i * 4096 + wv * 1024),
                16, 0, 0);
        }
    };

    stage(0, 0);
    __syncthreads();

    int cur = 0;
    for (int s = 0; s < nsteps; ++s) {
        if (s + 1 < nsteps) stage(cur ^ 1, s + 1);

        const short* ab = As + cur * 4096;
        const short* bb = Bs + cur * (NT * 1024);
        bf16x8 a[4], b[NT];
#pragma unroll
        for (int mt = 0; mt < 4; ++mt)
            a[mt] = load_frag(ab + (wr * 64 + mt * 16 + ln) * 32 + lq * 8);
#pragma unroll
        for (int nt = 0; nt < NT; ++nt)
            b[nt] = load_frag(bb + (wc * (NT * 16) + nt * 16 + ln) * 32 + lq * 8);
#pragma unroll
        for (int mt = 0; mt < 4; ++mt)
#pragma unroll
            for (int nt = 0; nt < NT; ++nt)
                acc[mt][nt] = __builtin_amdgcn_mfma_f32_16x16x32_bf16(
                    a[mt], b[nt], acc[mt][nt], 0, 0, 0);

        __syncthreads();
        cur ^= 1;
    }

#pragma unroll
    for (int mt = 0; mt < 4; ++mt) {
        const int ocr = oc0 + wr * 64 + mt * 16 + lq * 4;
        float bb[4];
        if (EPI == 1) {
            const float4 bv = *(const float4*)(bias + ocr);
            bb[0] = bv.x; bb[1] = bv.y; bb[2] = bv.z; bb[3] = bv.w;
        }
#pragma unroll
        for (int nt = 0; nt < NT; ++nt) {
            const int nl = wc * (NT * 16) + nt * 16 + ln;
            const int x = x0 + (nl & 31);
            const int y = y0 + (nl >> 5);
            if (x >= 100) continue;
            if (EPI == 1) {
                float v[4];
#pragma unroll
                for (int r = 0; r < 4; ++r) {
                    float tv = acc[mt][nt][r] + bb[r];
                    if (ACT) tv = gelu_exact(tv);
                    v[r] = tv;
                }
                ushort4 pk;
                pk.x = f2bf(v[0]); pk.y = f2bf(v[1]); pk.z = f2bf(v[2]); pk.w = f2bf(v[3]);
                *(ushort4*)(outcl + ((size_t)(y + OPAD) * OPW + (x + OPAD)) * COUT + ocr) = pk;
            } else {
                const int pix = y * WID + x;
#pragma unroll
                for (int r = 0; r < 4; ++r)
                    outcm[((size_t)ks * COUT + ocr + r) * HW + pix] = acc[mt][nt][r];
            }
        }
    }
}

// fused: out = inorm(bias + res + sum_z slab[z])
template<int NS>
__global__ __launch_bounds__(256)
void red_norm_k(const float* __restrict__ bias, const float* __restrict__ res,
                const float* __restrict__ slab, float* __restrict__ outp)
{
    const int c = blockIdx.x, tid = threadIdx.x;
    const size_t base = (size_t)c * HW;
    const float bc = bias[c];
    float v[40];
    float s1 = 0.f, s2 = 0.f;
#pragma unroll
    for (int k = 0; k < 40; ++k) {
        const int i = tid + k * 256;
        float x = 0.f;
        if (i < HW) {
            x = bc + res[base + i];
#pragma unroll
            for (int z = 0; z < NS; ++z) x += slab[(size_t)z * 1280000 + base + i];
            s1 += x; s2 += x * x;
        }
        v[k] = x;
    }
    __shared__ float r1[256], r2[256];
    r1[tid] = s1; r2[tid] = s2; __syncthreads();
    for (int o = 128; o > 0; o >>= 1) {
        if (tid < o) { r1[tid] += r1[tid + o]; r2[tid] += r2[tid + o]; }
        __syncthreads();
    }
    const float mean = r1[0] * 1e-4f;
    const float var  = fmaxf(r2[0] * 1e-4f - mean * mean, 0.f);
    const float rstd = rsqrtf(var + 1e-5f);
#pragma unroll
    for (int k = 0; k < 40; ++k) {
        const int i = tid + k * 256;
        if (i < HW) outp[base + i] = (v[k] - mean) * rstd;
    }
}

// zero only the 1-px pad rings of sf_cl (102x102x256) and m2_cl (102x102x512)
__global__ void zero_borders(short* __restrict__ sf_cl, short* __restrict__ m2_cl)
{
    const int NSF = 404 * 32;          // 16B vectors in sf ring
    const int NM2 = 404 * 64;          // 16B vectors in m2 ring
    const uint4v z = {0u, 0u, 0u, 0u};
    for (int i = blockIdx.x * blockDim.x + threadIdx.x; i < NSF + NM2;
         i += gridDim.x * blockDim.x) {
        short* base; int pb, vc, C;
        if (i < NSF) { base = sf_cl; pb = i >> 5; vc = i & 31; C = 256; }
        else { const int j = i - NSF; base = m2_cl; pb = j >> 6; vc = j & 63; C = 512; }
        int y, x;
        if (pb < 102)      { y = 0;            x = pb; }
        else if (pb < 204) { y = 101;          x = pb - 102; }
        else if (pb < 304) { y = pb - 204 + 1; x = 0; }
        else               { y = pb - 304 + 1; x = 101; }
        *(uint4v*)(base + (size_t)(y * 102 + x) * C + vc * 8) = z;
    }
}

// bev_query fp32 [128][100][100] -> x_cat bf16 channel-last padded(2)
__global__ void pad_cat_x(const float* __restrict__ in, short* __restrict__ out)
{
    const int total = 10816 * 384;
    for (int i = blockIdx.x * blockDim.x + threadIdx.x; i < total; i += gridDim.x * blockDim.x) {
        const int c = i % 384;
        const int p = i / 384;
        const int x = p % 104 - 2;
        const int y = p / 104 - 2;
        const int sc = c & 127;
        float v = 0.f;
        if (x >= 0 && x < 100 && y >= 0 && y < 100) v = in[(size_t)sc * HW + y * WID + x];
        const unsigned short hi = f2bf(v);
        short o;
        if (c >= 128 && c < 256) o = (short)f2bf(v - bf2f((short)hi));
        else                     o = (short)hi;
        out[i] = o;
    }
}

template<int C, int PAD>
__global__ void pad_cl_cast(const float* __restrict__ in, short* __restrict__ out)
{
    constexpr int PW = 100 + 2 * PAD;
    const int total = PW * PW * C;
    for (int i = blockIdx.x * blockDim.x + threadIdx.x; i < total; i += gridDim.x * blockDim.x) {
        const int c = i % C;
        const int p = i / C;
        const int x = p % PW - PAD;
        const int y = p / PW - PAD;
        float v = 0.f;
        if (x >= 0 && x < 100 && y >= 0 && y < 100) v = in[(size_t)c * HW + y * WID + x];
        out[i] = (short)f2bf(v);
    }
}

// mid/out weights -> bf16 packed; 5th segment = in_w split-cat (hi/hi/lo)
__global__ void pack_all_bf16(const float* __restrict__ w1, const float* __restrict__ w2,
                              const float* __restrict__ w3, const float* __restrict__ w4,
                              const float* __restrict__ wc,
                              short* __restrict__ out, short* __restrict__ outc)
{
    const int E0 = 1179648, E1 = E0 + 262144, E2 = E1 + 589824, E3 = E2 + 409600;
    const int E4 = E3 + 1228800;
    for (int i = blockIdx.x * blockDim.x + threadIdx.x; i < E4; i += gridDim.x * blockDim.x) {
        if (i < E3) {
            const float* w; int OC, CI, KS, j;
            if (i < E0)      { w = w1; OC = 512; CI = 256; KS = 3; j = i; }
            else if (i < E1) { w = w2; OC = 512; CI = 512; KS = 1; j = i - E0; }
            else if (i < E2) { w = w3; OC = 128; CI = 512; KS = 3; j = i - E1; }
            else             { w = w4; OC = 128; CI = 128; KS = 5; j = i - E2; }
            const int ic = j % CI;
            int t = j / CI;
            const int oc = t % OC;
            const int s = t / OC;
            const int ky = s / KS, kx = s % KS;
            out[i] = (short)f2bf(w[(((size_t)oc * CI + ic) * KS + ky) * KS + kx]);
        } else {
            const int j = i - E3;
            const int c = j % 384;
            int t = j / 384;
            const int oc = t % 128;
            const int s = t / 128;
            const int ky = s / 5, kx = s % 5;
            const int sc = c & 127;
            const float v = wc[(((size_t)oc * 128 + sc) * 5 + ky) * 5 + kx];
            const unsigned short hi = f2bf(v);
            outc[j] = (c < 256) ? (short)hi : (short)f2bf(v - bf2f((short)hi));
        }
    }
}

// feature transposes -> bf16 channel-last, concatenated
__global__ void transpose_all(const float* __restrict__ f0, const float* __restrict__ f1,
                              const float* __restrict__ f2, const float* __restrict__ f3,
                              short* __restrict__ out)
{
    const int O1 = 2230272, O2 = O1 + 557568, O3 = O2 + 139392, O4 = O3 + 34848;
    for (int i = blockIdx.x * blockDim.x + threadIdx.x; i < O4; i += gridDim.x * blockDim.x) {
        const float* f; int Hl, Wl, j;
        if (i < O1)      { f = f0; Hl = 32; Wl = 88; j = i; }
        else if (i < O2) { f = f1; Hl = 16; Wl = 44; j = i - O1; }
        else if (i < O3) { f = f2; Hl = 8;  Wl = 22; j = i - O2; }
        else             { f = f3; Hl = 4;  Wl = 11; j = i - O3; }
        const int c = j % 132;
        int t = j / 132;
        const int x = t % Wl; t /= Wl;
        const int y = t % Hl; t /= Hl;
        const int n = t;
        out[i] = (short)f2bf(f[(((size_t)n * 132 + c) * Hl + y) * Wl + x]);
    }
}

// offsw + projection compaction fused (unchanged)
__global__ __launch_bounds__(64)
void offsw_proj(const float* __restrict__ qn, const float* __restrict__ bev_pos,
                const float* __restrict__ off_w, const float* __restrict__ off_b,
                const float* __restrict__ sw_w, const float* __restrict__ sw_b,
                const float* __restrict__ l2i,
                float* __restrict__ refp, float* __restrict__ swts,
                float2* __restrict__ recs, int* __restrict__ recn, int* __restrict__ cnts)
{
    const int pix = blockIdx.x;
    const int tid = threadIdx.x;
    __shared__ float qv[128];
    __shared__ float swraw[32];
    __shared__ float rp[24];
    qv[tid]      = qn[(size_t)tid * HW + pix];
    qv[tid + 64] = qn[(size_t)(tid + 64) * HW + pix];
    __syncthreads();

    if (tid < 24) {
        float acc = off_b[tid];
        for (int c = 0; c < 128; ++c) acc = fmaf(qv[c], off_w[tid * 128 + c], acc);
        const float s = 1.0f / (1.0f + expf(-acc));
        const int coord = tid % 3;
        const float rng = (coord < 2) ? 0.250001f : 4.000001f;
        const float v = s * rng * 2.0f - rng;
        const float lo[3]   = {-50.f, -50.f, -5.f};
        const float span[3] = {100.f, 100.f, 8.f};
        const float rv = bev_pos[pix * 3 + coord] * span[coord] + lo[coord] + v;
        refp[pix * 24 + tid] = rv;
        rp[tid] = rv;
    } else if (tid >= 32) {
        const int j = tid - 32;
        float acc = sw_b[j];
        for (int c = 0; c < 128; ++c) acc = fmaf(qv[c], sw_w[j * 128 + c], acc);
        swraw[j] = acc;
    }
    __syncthreads();
    if (tid < 8) {
        float m = -1e30f;
#pragma unroll
        for (int l = 0; l < 4; ++l) m = fmaxf(m, swraw[tid * 4 + l]);
        float e[4], sum = 0.f;
#pragma unroll
        for (int l = 0; l < 4; ++l) { e[l] = expf(swraw[tid * 4 + l] - m); sum += e[l]; }
        const float inv = 1.0f / sum;
#pragma unroll
        for (int l = 0; l < 4; ++l) swts[pix * 32 + tid * 4 + l] = e[l] * inv;
    }

    bool keep = false;
    float gx = -2.f, gy = -2.f;
    int p = 0, n = 0;
    if (tid < 48) {
        p = tid / 6;
        n = tid - p * 6;
        const float X = rp[p * 3 + 0], Y = rp[p * 3 + 1], Z = rp[p * 3 + 2];
        const float* m = l2i + n * 16;
        const float cx = m[0] * X + m[1] * Y + m[2]  * Z + m[3];
        const float cy = m[4] * X + m[5] * Y + m[6]  * Z + m[7];
        const float cz = m[8] * X + m[9] * Y + m[10] * Z + m[11];
        const bool valid = cz > 1e-5f;
        const float zz = fmaxf(cz, 1e-5f);
        gx = valid ? (cx / zz) * (2.0f / 704.0f) - 1.0f : -2.0f;
        gy = valid ? (cy / zz) * (2.0f / 256.0f) - 1.0f : -2.0f;
        keep = (gx > -1.092f) && (gx < 1.092f) && (gy > -1.26f) && (gy < 1.26f);
    }
    const unsigned long long bm = __ballot(keep);
    if (keep) {
        const unsigned long long gmask = 0x3Full << (p * 6);
        const int slot = __popcll(bm & ((1ull << tid) - 1ull) & gmask);
        recs[(size_t)pix * 48 + p * 6 + slot] = make_float2(gx, gy);
        recn[(size_t)pix * 48 + p * 6 + slot] = n;
    }
    if (tid < 48 && (tid % 6) == 0) {
        const unsigned long long gmask = 0x3Full << (p * 6);
        cnts[pix * 8 + p] = __popcll(bm & gmask);
    }
}

// ---------------------------------------------------------------------------
// sample_k4 — round-16 v2 verbatim: no divergent tail, 1-deep register
// prefetch over r, weights in registers.
// ---------------------------------------------------------------------------
__global__ __launch_bounds__(64)
void sample_k4(const float* __restrict__ refp, const float* __restrict__ swts,
               const float2* __restrict__ recs, const int* __restrict__ recn,
               const int* __restrict__ cnts,
               const short* __restrict__ fb0,   // concatenated bf16 feats
               short* __restrict__ sfo)
{
    const int pix = blockIdx.x;
    const int tid = threadIdx.x;                   // 64
    const int c0  = tid * 2;                       // channels c0, c0+1
    __shared__ float rp[24], sw[32], tail[32];
    __shared__ float2 rec[48];
    __shared__ int rn[48];
    __shared__ int cnt[8];
    __shared__ int4   toff[192];
    __shared__ float4 twt[192];
    if (tid < 24) rp[tid] = refp[pix * 24 + tid];
    if (tid < 32) sw[tid] = swts[pix * 32 + tid];
    if (tid < 48) { rec[tid] = recs[(size_t)pix * 48 + tid]; rn[tid] = recn[(size_t)pix * 48 + tid]; }
    if (tid < 8)  cnt[tid] = cnts[pix * 8 + tid];
    __syncthreads();

    const int HL[4] = {32, 16, 8, 4};
    const int WL[4] = {88, 44, 22, 11};
    const int LB[4] = {0, 2230272, 2787840, 2927232};   // level bases (shorts)

    for (int e = tid; e < 192; e += 64) {
        const int p  = e / 24;
        const int rl = e - p * 24;
        const int r  = rl >> 2;
        const int l  = rl & 3;
        int4 off = make_int4(0, 0, 0, 0);
        float4 wt = make_float4(0.f, 0.f, 0.f, 0.f);
        if (r < cnt[p]) {
            const float gx = rec[p * 6 + r].x;
            const float gy = rec[p * 6 + r].y;
            const int   n  = rn[p * 6 + r];
            const float wl = sw[p * 4 + l];
            const int Hl = HL[l], Wl = WL[l];
            const float fx = (gx + 1.0f) * 0.5f * (float)Wl - 0.5f;
            const float fy = (gy + 1.0f) * 0.5f * (float)Hl - 0.5f;
            if (fx >= -1.0f && fx < (float)Wl && fy >= -1.0f && fy < (float)Hl) {
                const float x0f = floorf(fx), y0f = floorf(fy);
                const int x0 = (int)x0f, y0 = (int)y0f;
                const int x1 = x0 + 1, y1 = y0 + 1;
                const float wx1 = fx - x0f, wy1 = fy - y0f;
                const float wx0 = 1.0f - wx1, wy0 = 1.0f - wy1;
                const bool okx0 = (x0 >= 0), okx1 = (x1 < Wl);
                const bool oky0 = (y0 >= 0), oky1 = (y1 < Hl);
                const int xc0 = okx0 ? x0 : 0, xc1 = okx1 ? x1 : Wl - 1;
                const int yc0 = oky0 ? y0 : 0, yc1 = oky1 ? y1 : Hl - 1;
                const int base = LB[l] + n * Hl * Wl * 132;
                off.x = base + (yc0 * Wl + xc0) * 132;
                off.y = base + (yc0 * Wl + xc1) * 132;
                off.z = base + (yc1 * Wl + xc0) * 132;
                off.w = base + (yc1 * Wl + xc1) * 132;
                wt.x = (okx0 && oky0) ? wx0 * wy0 * wl : 0.f;
                wt.y = (okx1 && oky0) ? wx1 * wy0 * wl : 0.f;
                wt.z = (okx0 && oky1) ? wx0 * wy1 * wl : 0.f;
                wt.w = (okx1 && oky1) ? wx1 * wy1 * wl : 0.f;
            }
        }
        toff[e] = off;
        twt[e]  = wt;
    }
    __syncthreads();

    // load one r-batch (16 taps + 16 weights) into static registers
#define LOADB(L, W, P, R)                                                        \
    do {                                                                         \
        const int eb_ = (P) * 24 + (R) * 4;                                      \
        _Pragma("unroll")                                                        \
        for (int l = 0; l < 4; ++l) {                                            \
            const int4 offv_ = toff[eb_ + l];                                    \
            W[l] = twt[eb_ + l];                                                 \
            const int ox_ = __builtin_amdgcn_readfirstlane(offv_.x);             \
            const int oy_ = __builtin_amdgcn_readfirstlane(offv_.y);             \
            const int oz_ = __builtin_amdgcn_readfirstlane(offv_.z);             \
            const int ow_ = __builtin_amdgcn_readfirstlane(offv_.w);             \
            L[l * 4 + 0] = *(const unsigned int*)(fb0 + ox_ + c0);               \
            L[l * 4 + 1] = *(const unsigned int*)(fb0 + oy_ + c0);               \
            L[l * 4 + 2] = *(const unsigned int*)(fb0 + oz_ + c0);               \
            L[l * 4 + 3] = *(const unsigned int*)(fb0 + ow_ + c0);               \
        }                                                                        \
    } while (0)

#define FMAB(L, W)                                                               \
    do {                                                                         \
        _Pragma("unroll")                                                        \
        for (int l = 0; l < 4; ++l) {                                            \
            a0.x = fmaf(__uint_as_float(L[l * 4 + 0] << 16),          W[l].x, a0.x); \
            a0.y = fmaf(__uint_as_float(L[l * 4 + 0] & 0xFFFF0000u),  W[l].x, a0.y); \
            a1.x = fmaf(__uint_as_float(L[l * 4 + 1] << 16),          W[l].y, a1.x); \
            a1.y = fmaf(__uint_as_float(L[l * 4 + 1] & 0xFFFF0000u),  W[l].y, a1.y); \
            a2.x = fmaf(__uint_as_float(L[l * 4 + 2] << 16),          W[l].z, a2.x); \
            a2.y = fmaf(__uint_as_float(L[l * 4 + 2] & 0xFFFF0000u),  W[l].z, a2.y); \
            a3.x = fmaf(__uint_as_float(L[l * 4 + 3] << 16),          W[l].w, a3.x); \
            a3.y = fmaf(__uint_as_float(L[l * 4 + 3] & 0xFFFF0000u),  W[l].w, a3.y); \
        }                                                                        \
    } while (0)

    float2 acc[8];
#pragma unroll
    for (int p = 0; p < 8; ++p) {
        float2 a0 = {0.f, 0.f}, a1 = {0.f, 0.f}, a2 = {0.f, 0.f}, a3 = {0.f, 0.f};
        const int c = cnt[p];
        unsigned int LA[16]; float4 WA[4];
        if (c > 0) LOADB(LA, WA, p, 0);
        int r = 0;
        while (r < c) {
            unsigned int LB2[16]; float4 WB[4];
            if (r + 1 < c) LOADB(LB2, WB, p, r + 1);
            FMAB(LA, WA);
            ++r;
            if (r >= c) break;
            if (r + 1 < c) LOADB(LA, WA, p, r + 1);
            FMAB(LB2, WB);
            ++r;
        }
        acc[p].x = (a0.x + a1.x) + (a2.x + a3.x);
        acc[p].y = (a0.y + a1.y) + (a2.y + a3.y);
    }
#undef LOADB
#undef FMAB

    // tail channels 128..130 (pos3d): tap-parallel, 8 lanes per point
    {
        const int p   = tid >> 3;
        const int sub = tid & 7;
        const int c   = cnt[p];
        const int nslots = c * 16;              // (4 levels * c rows) entries x 4 taps
        float t0 = 0.f, t1 = 0.f, t2 = 0.f;
        for (int s = sub; s < nslots; s += 8) {
            const int e  = p * 24 + (s >> 2);
            const int tp = s & 3;
            const int4   offv = toff[e];
            const float4 wtv  = twt[e];
            const int   off = (tp == 0) ? offv.x : (tp == 1) ? offv.y : (tp == 2) ? offv.z : offv.w;
            const float w   = (tp == 0) ? wtv.x  : (tp == 1) ? wtv.y  : (tp == 2) ? wtv.z  : wtv.w;
            const uint2 u = *(const uint2*)(fb0 + off + 128);   // ch128..131 (8B aligned)
            t0 = fmaf(__uint_as_float(u.x << 16),         w, t0);
            t1 = fmaf(__uint_as_float(u.x & 0xFFFF0000u), w, t1);
            t2 = fmaf(__uint_as_float(u.y << 16),         w, t2);
        }
#pragma unroll
        for (int o = 4; o > 0; o >>= 1) {
            t0 += __shfl_down(t0, o, 8);
            t1 += __shfl_down(t1, o, 8);
            t2 += __shfl_down(t2, o, 8);
        }
        if (sub == 0) {
            tail[p * 4 + 0] = t0;
            tail[p * 4 + 1] = t1;
            tail[p * 4 + 2] = t2;
        }
    }
    __syncthreads();

    float2 sf1 = {0.f, 0.f}, sf2 = {0.f, 0.f};
#pragma unroll
    for (int p = 0; p < 8; ++p) {
        const float dx = rp[p * 3]     - tail[p * 4 + 0];
        const float dy = rp[p * 3 + 1] - tail[p * 4 + 1];
        const float dz = rp[p * 3 + 2] - tail[p * 4 + 2];
        const float wgt = expf(-0.1f * (dx * dx + dy * dy + dz * dz));
        sf1.x += acc[p].x;  sf1.y += acc[p].y;
        sf2.x += acc[p].x * wgt;  sf2.y += acc[p].y * wgt;
    }
    const int y = pix / WID, x = pix % WID;
    const size_t po = ((size_t)(y + 1) * 102 + (x + 1)) * 256;
    ushort2 p1; p1.x = f2bf(sf1.x); p1.y = f2bf(sf1.y);
    ushort2 p2; p2.x = f2bf(sf2.x); p2.y = f2bf(sf2.y);
    *(ushort2*)(sfo + po + c0)       = p1;
    *(ushort2*)(sfo + po + 128 + c0) = p2;
}

// ---------------------------------------------------------------------------

extern "C" void kernel_launch(void* const* d_in, const int* in_sizes, int n_in,
                              void* d_out, int out_size, void* d_ws, size_t ws_size,
                              hipStream_t stream)
{
    const float* bev_query = (const float*)d_in[0];
    const float* bev_pos   = (const float*)d_in[1];
    const float* l2i       = (const float*)d_in[2];
    const float* feat0     = (const float*)d_in[3];
    const float* feat1     = (const float*)d_in[4];
    const float* feat2     = (const float*)d_in[5];
    const float* feat3     = (const float*)d_in[6];
    const float* in_w      = (const float*)d_in[7];
    const float* in_b      = (const float*)d_in[8];
    const float* off_w     = (const float*)d_in[9];
    const float* off_b     = (const float*)d_in[10];
    const float* sw_w      = (const float*)d_in[11];
    const float* sw_b      = (const float*)d_in[12];
    const float* mid_w1    = (const float*)d_in[13];
    const float* mid_b1    = (const float*)d_in[14];
    const float* mid_w2    = (const float*)d_in[15];
    const float* mid_b2    = (const float*)d_in[16];
    const float* mid_w3    = (const float*)d_in[17];
    const float* mid_b3    = (const float*)d_in[18];
    const float* out_w     = (const float*)d_in[19];
    const float* out_b     = (const float*)d_in[20];
    float* out = (float*)d_out;

    // ---- workspace layout (lifetime-aliased) ----
    float* ws    = (float*)d_ws;
    float* qn    = ws;                       // 1,280,000
    float* refp  = qn + 1280000;             //   240,000
    float* swts  = refp + 240000;            //   320,000
    float* E     = swts + 320000;            // 6,400,000 (slab5 | fTb+recs | m1_cl | slab3/5)
    float* F     = E + 6400000;              // 1,800,000 (xcat+wcat | sf_cl | q2pad)
    float* H     = F + 1800000;              // 2,700,000 (wcat tail | m2_cl)
    short* wp_all= (short*)(H + 2700000);    // 2,441,216 sh

    float*  slab  = E;                       // conv1/conv4: 5 slabs; conv3: 3 slabs
    short*  fT0   = (short*)E;               // 2,962,080 shorts (bf16 feats, concatenated)
    float2* recs  = (float2*)(E + 1600000);  // 480,000 f2
    int*    recn  = (int*)(E + 2560000);     // 480,000
    int*    cnts  = (int*)(E + 3040000);     //  80,000
    short*  m1_cl = (short*)E;               // 5,120,000 sh [100][100][512]
    short*  xcat  = (short*)F;               // 4,153,344 sh [104][104][384] hi/lo/hi
    short*  wcat  = (short*)(F + 2100000);   // 1,228,800 sh (spills into H; dead by m2)
    short*  sf_cl = (short*)F;               // 2,663,424 sh [102][102][256]
    short*  q2pad = (short*)F;               // 1,384,448 sh [104][104][128]
    short*  m2_cl = (short*)H;               // 5,326,848 sh [102][102][512]
    short*  wp_m1 = wp_all;                  // 1,179,648
    short*  wp_m2 = wp_m1 + 1179648;         //   262,144
    short*  wp_m3 = wp_m2 + 262144;          //   589,824
    short*  wp_out= wp_m3 + 589824;          //   409,600

    const dim3 blk(256);

    // ---- weight packing (all bf16 packs in one kernel) ----
    hipLaunchKernelGGL(pack_all_bf16, dim3(14336), blk, 0, stream,
                       mid_w1, mid_w2, mid_w3, out_w, in_w, wp_all, wcat);

    // ---- 1. q1 slabs = conv5x5 split-bf16 MFMA, then qn = inorm fused ----
    hipLaunchKernelGGL(pad_cat_x, dim3(4056), blk, 0, stream, bev_query, xcat);
    hipLaunchKernelGGL((mfma_conv<384, 5, 128, 2, false, 0, 0, 5, 2>), dim3(1, 50, 20), blk, 0, stream,
                       wcat, xcat, in_b, slab, nullptr);
    hipLaunchKernelGGL(red_norm_k<5>, dim3(128), blk, 0, stream, in_b, bev_query, slab, qn);

    // ---- pad-ring zeroing (xcat/wcat dead after conv1) ----
    hipLaunchKernelGGL(zero_borders, dim3(152), blk, 0, stream, sf_cl, m2_cl);

    // ---- 2. ref points + softmax weights + projection compaction ----
    hipLaunchKernelGGL(offsw_proj, dim3(HW), dim3(64), 0, stream,
                       qn, bev_pos, off_w, off_b, sw_w, sw_b, l2i,
                       refp, swts, recs, recn, cnts);

    // ---- 3. feature transposes -> bf16 (slab5 dead) ----
    hipLaunchKernelGGL(transpose_all, dim3(11571), blk, 0, stream,
                       feat0, feat1, feat2, feat3, fT0);

    // ---- 4. sampling -> sf_cl bf16 padded(1) ----
    hipLaunchKernelGGL(sample_k4, dim3(HW), dim3(64), 0, stream,
                       refp, swts, recs, recn, cnts, fT0, sf_cl);

    // ---- 5. m1 = gelu(conv3x3 256->512), NT=2: 800 blocks ----
    hipLaunchKernelGGL((mfma_conv<256, 3, 512, 1, true, 0, 100, 1, 2>), dim3(4, 50, 4), blk, 0, stream,
                       wp_m1, sf_cl, mid_b1, nullptr, m1_cl);
    // ---- 6. m2 = gelu(conv1x1 512->512) -> padded(1), NT=2: 800 blocks ----
    hipLaunchKernelGGL((mfma_conv<512, 1, 512, 1, true, 1, 102, 1, 2>), dim3(4, 50, 4), blk, 0, stream,
                       wp_m2, m1_cl, mid_b2, nullptr, m2_cl);
    // ---- 7. q2 = inorm(qn + conv3x3 512->128), NT=2: 600 blocks ----
    hipLaunchKernelGGL((mfma_conv<512, 3, 128, 2, false, 0, 0, 3, 2>), dim3(1, 50, 12), blk, 0, stream,
                       wp_m3, m2_cl, mid_b3, slab, nullptr);
    hipLaunchKernelGGL(red_norm_k<3>, dim3(128), blk, 0, stream, mid_b3, qn, slab, qn);
    // ---- 8. q3 = inorm(qn + conv5x5 bf16), NT=2 + KSPLIT=5: 1000 blocks ----
    hipLaunchKernelGGL((pad_cl_cast<128, 2>), dim3(5411), blk, 0, stream, qn, q2pad);
    hipLaunchKernelGGL((mfma_conv<128, 5, 128, 2, false, 0, 0, 5, 2>), dim3(1, 50, 20), blk, 0, stream,
                       wp_out, q2pad, out_b, slab, nullptr);
    hipLaunchKernelGGL(red_norm_k<5>, dim3(128), blk, 0, stream, out_b, qn, slab, out);
}

// Round 11
// 504.333 us; speedup vs baseline: 1.1147x; 1.0138x over previous
//
#include <hip/hip_runtime.h>
#include <cstddef>

// ---------------------------------------------------------------------------
// SegTransformerDecoder — round 23 (r22 + depth-2 counted-vmcnt conv pipeline).
//  * mfma_conv: 3 LDS buffers (36KB), depth-2 prefetch, counted
//    s_waitcnt vmcnt(3) + raw s_barrier instead of __syncthreads' vmcnt(0)
//    drain. Stage s is waited only after stage s+1 has a full compute phase
//    in flight. Safety: 3 uniform loads/thread/stage; vmcnt oldest-first
//    (m135) => vmcnt(3) == "stage s done"; barrier makes it cross-wave;
//    buf (s+2)%3 overwritten only after all waves' iter-(s-1) reads.
//    Math order untouched -> bit-identical. (r20 added LDS without async
//    depth and lost TLP; this adds the depth that makes 4 blocks/CU enough.)
//  * Everything else identical to r22 (511.3us best: zero_borders, fused
//    packs, BK=32 NT=2 convs, r16-v2 sampler).
// ---------------------------------------------------------------------------

#define HW   10000
#define WID  100

typedef __attribute__((ext_vector_type(8))) __bf16 bf16x8;
typedef __attribute__((ext_vector_type(4))) float f32x4;
typedef __attribute__((ext_vector_type(4))) unsigned int uint4v;

#define AS1 __attribute__((address_space(1)))
#define AS3 __attribute__((address_space(3)))

__device__ __forceinline__ float gelu_exact(float x) {
    return 0.5f * x * (1.0f + erff(x * 0.7071067811865475f));
}
__device__ __forceinline__ unsigned short f2bf(float v) {
    unsigned int b = __float_as_uint(v);
    return (unsigned short)((b + 0x7FFFu + ((b >> 16) & 1u)) >> 16);
}
__device__ __forceinline__ float bf2f(short s) {
    return __uint_as_float(((unsigned int)(unsigned short)s) << 16);
}
__device__ __forceinline__ bf16x8 load_frag(const short* p) {
    return __builtin_bit_cast(bf16x8, *(const uint4v*)p);
}

// ---------------------------------------------------------------------------
// bf16 MFMA implicit-GEMM conv, LDS-staged, BK=32, NT pixel rows.
// 3-buffer depth-2 async pipeline with counted vmcnt.
// ---------------------------------------------------------------------------
template<int CIN, int KS, int COUT, int EPI, bool ACT, int OPAD, int OPW, int KSPLIT, int NT>
__global__ __launch_bounds__(256)
void mfma_conv(const short* __restrict__ wpk, const short* __restrict__ xcl,
               const float* __restrict__ bias,
               float* __restrict__ outcm, short* __restrict__ outcl)
{
    constexpr int PW = 100 + 2 * (KS / 2);
    constexpr int CHUNK = (KS + KSPLIT - 1) / KSPLIT;
    constexpr int CINB = CIN / 32;          // ic0 steps per (ky,kx)
    constexpr int BBUF = NT * 2048;         // Bs buffer stride in BYTES
    __shared__ short As[12288];             // 3 buffers x [128 oc][32 ic]
    __shared__ short Bs[NT * 3072];         // 3 buffers x [NT*32 pix][32 ic]

    const int t    = threadIdx.x;
    const int lane = t & 63;
    const int wv   = t >> 6;
    const int wr = wv >> 1;
    const int wc = wv & 1;
    const int lq = lane >> 4;
    const int ln = lane & 15;

    const int oc0 = blockIdx.x * 128;
    const int y0  = blockIdx.y * NT;
    const int zb  = blockIdx.z;
    const int bx  = (KSPLIT > 1) ? (zb & 3) : zb;
    const int ks  = (KSPLIT > 1) ? (zb >> 2) : 0;
    const int x0  = bx * 32;
    const int ky_lo = ks * CHUNK;
    const int ky_hi = (ky_lo + CHUNK < KS) ? ky_lo + CHUNK : KS;

    const int srow  = t >> 2;               // 0..63
    const int sslot = (t & 3) * 8;          // shorts (4 x 16B per 64B row)

    const int nsteps = (ky_hi - ky_lo) * KS * CINB;

    f32x4 acc[4][NT];
#pragma unroll
    for (int mt = 0; mt < 4; ++mt)
#pragma unroll
        for (int nt = 0; nt < NT; ++nt)
#pragma unroll
            for (int r = 0; r < 4; ++r) acc[mt][nt][r] = 0.f;

    // stage step s into buffer b: 3 global_load_lds per thread (A:2, B:1)
    auto stage = [&](int b, int s) {
        const int ky  = ky_lo + s / (KS * CINB);
        const int rem = s % (KS * CINB);
        const int kx  = rem / CINB;
        const int ic0 = (rem % CINB) * 32;
        const short* wsl = wpk + (size_t)((ky * KS + kx) * COUT + oc0) * CIN + ic0 + sslot;
        const short* xsl = xcl + (size_t)(ky * PW + kx) * CIN + ic0 + sslot;
#pragma unroll
        for (int i = 0; i < 2; ++i) {
            const int row = i * 64 + srow;
            const short* ga = wsl + (size_t)row * CIN;
            __builtin_amdgcn_global_load_lds(
                (const AS1 unsigned int*)ga,
                (AS3 unsigned int*)((AS3 char*)As + b * 8192 + i * 4096 + wv * 1024),
                16, 0, 0);
        }
#pragma unroll
        for (int i = 0; i < NT / 2; ++i) {
            const int np = i * 64 + srow;
            const short* gb = xsl + (size_t)((y0 + (np >> 5)) * PW + x0 + (np & 31)) * CIN;
            __builtin_amdgcn_global_load_lds(
                (const AS1 unsigned int*)gb,
                (AS3 unsigned int*)((AS3 char*)Bs + b * BBUF + i * 4096 + wv * 1024),
                16, 0, 0);
        }
    };

    stage(0, 0);
    if (nsteps > 1) stage(1, 1);

    for (int s = 0; s < nsteps; ++s) {
        const int cur = s % 3;
        // wait for stage s (oldest in flight); leave stage s+1 outstanding
        if (s + 1 < nsteps) {
            asm volatile("s_waitcnt vmcnt(3)" ::: "memory");
        } else {
            asm volatile("s_waitcnt vmcnt(0)" ::: "memory");
        }
        __builtin_amdgcn_s_barrier();   // all waves' stage-s writes visible;
                                        // also: all waves done reading buf (s-1)%3

        const short* ab = As + cur * 4096;
        const short* bb = Bs + cur * (NT * 1024);
        bf16x8 a[4], b[NT];
#pragma unroll
        for (int mt = 0; mt < 4; ++mt)
            a[mt] = load_frag(ab + (wr * 64 + mt * 16 + ln) * 32 + lq * 8);
#pragma unroll
        for (int nt = 0; nt < NT; ++nt)
            b[nt] = load_frag(bb + (wc * (NT * 16) + nt * 16 + ln) * 32 + lq * 8);
#pragma unroll
        for (int mt = 0; mt < 4; ++mt)
#pragma unroll
            for (int nt = 0; nt < NT; ++nt)
                acc[mt][nt] = __builtin_amdgcn_mfma_f32_16x16x32_bf16(
                    a[mt], b[nt], acc[mt][nt], 0, 0, 0);

        if (s + 2 < nsteps) stage((s + 2) % 3, s + 2);   // depth-2 prefetch
    }

#pragma unroll
    for (int mt = 0; mt < 4; ++mt) {
        const int ocr = oc0 + wr * 64 + mt * 16 + lq * 4;
        float bb[4];
        if (EPI == 1) {
            const float4 bv = *(const float4*)(bias + ocr);
            bb[0] = bv.x; bb[1] = bv.y; bb[2] = bv.z; bb[3] = bv.w;
        }
#pragma unroll
        for (int nt = 0; nt < NT; ++nt) {
            const int nl = wc * (NT * 16) + nt * 16 + ln;
            const int x = x0 + (nl & 31);
            const int y = y0 + (nl >> 5);
            if (x >= 100) continue;
            if (EPI == 1) {
                float v[4];
#pragma unroll
                for (int r = 0; r < 4; ++r) {
                    float tv = acc[mt][nt][r] + bb[r];
                    if (ACT) tv = gelu_exact(tv);
                    v[r] = tv;
                }
                ushort4 pk;
                pk.x = f2bf(v[0]); pk.y = f2bf(v[1]); pk.z = f2bf(v[2]); pk.w = f2bf(v[3]);
                *(ushort4*)(outcl + ((size_t)(y + OPAD) * OPW + (x + OPAD)) * COUT + ocr) = pk;
            } else {
                const int pix = y * WID + x;
#pragma unroll
                for (int r = 0; r < 4; ++r)
                    outcm[((size_t)ks * COUT + ocr + r) * HW + pix] = acc[mt][nt][r];
            }
        }
    }
}

// fused: out = inorm(bias + res + sum_z slab[z])
template<int NS>
__global__ __launch_bounds__(256)
void red_norm_k(const float* __restrict__ bias, const float* __restrict__ res,
                const float* __restrict__ slab, float* __restrict__ outp)
{
    const int c = blockIdx.x, tid = threadIdx.x;
    const size_t base = (size_t)c * HW;
    const float bc = bias[c];
    float v[40];
    float s1 = 0.f, s2 = 0.f;
#pragma unroll
    for (int k = 0; k < 40; ++k) {
        const int i = tid + k * 256;
        float x = 0.f;
        if (i < HW) {
            x = bc + res[base + i];
#pragma unroll
            for (int z = 0; z < NS; ++z) x += slab[(size_t)z * 1280000 + base + i];
            s1 += x; s2 += x * x;
        }
        v[k] = x;
    }
    __shared__ float r1[256], r2[256];
    r1[tid] = s1; r2[tid] = s2; __syncthreads();
    for (int o = 128; o > 0; o >>= 1) {
        if (tid < o) { r1[tid] += r1[tid + o]; r2[tid] += r2[tid + o]; }
        __syncthreads();
    }
    const float mean = r1[0] * 1e-4f;
    const float var  = fmaxf(r2[0] * 1e-4f - mean * mean, 0.f);
    const float rstd = rsqrtf(var + 1e-5f);
#pragma unroll
    for (int k = 0; k < 40; ++k) {
        const int i = tid + k * 256;
        if (i < HW) outp[base + i] = (v[k] - mean) * rstd;
    }
}

// zero only the 1-px pad rings of sf_cl (102x102x256) and m2_cl (102x102x512)
__global__ void zero_borders(short* __restrict__ sf_cl, short* __restrict__ m2_cl)
{
    const int NSF = 404 * 32;          // 16B vectors in sf ring
    const int NM2 = 404 * 64;          // 16B vectors in m2 ring
    const uint4v z = {0u, 0u, 0u, 0u};
    for (int i = blockIdx.x * blockDim.x + threadIdx.x; i < NSF + NM2;
         i += gridDim.x * blockDim.x) {
        short* base; int pb, vc, C;
        if (i < NSF) { base = sf_cl; pb = i >> 5; vc = i & 31; C = 256; }
        else { const int j = i - NSF; base = m2_cl; pb = j >> 6; vc = j & 63; C = 512; }
        int y, x;
        if (pb < 102)      { y = 0;            x = pb; }
        else if (pb < 204) { y = 101;          x = pb - 102; }
        else if (pb < 304) { y = pb - 204 + 1; x = 0; }
        else               { y = pb - 304 + 1; x = 101; }
        *(uint4v*)(base + (size_t)(y * 102 + x) * C + vc * 8) = z;
    }
}

// bev_query fp32 [128][100][100] -> x_cat bf16 channel-last padded(2)
__global__ void pad_cat_x(const float* __restrict__ in, short* __restrict__ out)
{
    const int total = 10816 * 384;
    for (int i = blockIdx.x * blockDim.x + threadIdx.x; i < total; i += gridDim.x * blockDim.x) {
        const int c = i % 384;
        const int p = i / 384;
        const int x = p % 104 - 2;
        const int y = p / 104 - 2;
        const int sc = c & 127;
        float v = 0.f;
        if (x >= 0 && x < 100 && y >= 0 && y < 100) v = in[(size_t)sc * HW + y * WID + x];
        const unsigned short hi = f2bf(v);
        short o;
        if (c >= 128 && c < 256) o = (short)f2bf(v - bf2f((short)hi));
        else                     o = (short)hi;
        out[i] = o;
    }
}

template<int C, int PAD>
__global__ void pad_cl_cast(const float* __restrict__ in, short* __restrict__ out)
{
    constexpr int PW = 100 + 2 * PAD;
    const int total = PW * PW * C;
    for (int i = blockIdx.x * blockDim.x + threadIdx.x; i < total; i += gridDim.x * blockDim.x) {
        const int c = i % C;
        const int p = i / C;
        const int x = p % PW - PAD;
        const int y = p / PW - PAD;
        float v = 0.f;
        if (x >= 0 && x < 100 && y >= 0 && y < 100) v = in[(size_t)c * HW + y * WID + x];
        out[i] = (short)f2bf(v);
    }
}

// mid/out weights -> bf16 packed; 5th segment = in_w split-cat (hi/hi/lo)
__global__ void pack_all_bf16(const float* __restrict__ w1, const float* __restrict__ w2,
                              const float* __restrict__ w3, const float* __restrict__ w4,
                              const float* __restrict__ wc,
                              short* __restrict__ out, short* __restrict__ outc)
{
    const int E0 = 1179648, E1 = E0 + 262144, E2 = E1 + 589824, E3 = E2 + 409600;
    const int E4 = E3 + 1228800;
    for (int i = blockIdx.x * blockDim.x + threadIdx.x; i < E4; i += gridDim.x * blockDim.x) {
        if (i < E3) {
            const float* w; int OC, CI, KS, j;
            if (i < E0)      { w = w1; OC = 512; CI = 256; KS = 3; j = i; }
            else if (i < E1) { w = w2; OC = 512; CI = 512; KS = 1; j = i - E0; }
            else if (i < E2) { w = w3; OC = 128; CI = 512; KS = 3; j = i - E1; }
            else             { w = w4; OC = 128; CI = 128; KS = 5; j = i - E2; }
            const int ic = j % CI;
            int t = j / CI;
            const int oc = t % OC;
            const int s = t / OC;
            const int ky = s / KS, kx = s % KS;
            out[i] = (short)f2bf(w[(((size_t)oc * CI + ic) * KS + ky) * KS + kx]);
        } else {
            const int j = i - E3;
            const int c = j % 384;
            int t = j / 384;
            const int oc = t % 128;
            const int s = t / 128;
            const int ky = s / 5, kx = s % 5;
            const int sc = c & 127;
            const float v = wc[(((size_t)oc * 128 + sc) * 5 + ky) * 5 + kx];
            const unsigned short hi = f2bf(v);
            outc[j] = (c < 256) ? (short)hi : (short)f2bf(v - bf2f((short)hi));
        }
    }
}

// feature transposes -> bf16 channel-last, concatenated
__global__ void transpose_all(const float* __restrict__ f0, const float* __restrict__ f1,
                              const float* __restrict__ f2, const float* __restrict__ f3,
                              short* __restrict__ out)
{
    const int O1 = 2230272, O2 = O1 + 557568, O3 = O2 + 139392, O4 = O3 + 34848;
    for (int i = blockIdx.x * blockDim.x + threadIdx.x; i < O4; i += gridDim.x * blockDim.x) {
        const float* f; int Hl, Wl, j;
        if (i < O1)      { f = f0; Hl = 32; Wl = 88; j = i; }
        else if (i < O2) { f = f1; Hl = 16; Wl = 44; j = i - O1; }
        else if (i < O3) { f = f2; Hl = 8;  Wl = 22; j = i - O2; }
        else             { f = f3; Hl = 4;  Wl = 11; j = i - O3; }
        const int c = j % 132;
        int t = j / 132;
        const int x = t % Wl; t /= Wl;
        const int y = t % Hl; t /= Hl;
        const int n = t;
        out[i] = (short)f2bf(f[(((size_t)n * 132 + c) * Hl + y) * Wl + x]);
    }
}

// offsw + projection compaction fused (unchanged)
__global__ __launch_bounds__(64)
void offsw_proj(const float* __restrict__ qn, const float* __restrict__ bev_pos,
                const float* __restrict__ off_w, const float* __restrict__ off_b,
                const float* __restrict__ sw_w, const float* __restrict__ sw_b,
                const float* __restrict__ l2i,
                float* __restrict__ refp, float* __restrict__ swts,
                float2* __restrict__ recs, int* __restrict__ recn, int* __restrict__ cnts)
{
    const int pix = blockIdx.x;
    const int tid = threadIdx.x;
    __shared__ float qv[128];
    __shared__ float swraw[32];
    __shared__ float rp[24];
    qv[tid]      = qn[(size_t)tid * HW + pix];
    qv[tid + 64] = qn[(size_t)(tid + 64) * HW + pix];
    __syncthreads();

    if (tid < 24) {
        float acc = off_b[tid];
        for (int c = 0; c < 128; ++c) acc = fmaf(qv[c], off_w[tid * 128 + c], acc);
        const float s = 1.0f / (1.0f + expf(-acc));
        const int coord = tid % 3;
        const float rng = (coord < 2) ? 0.250001f : 4.000001f;
        const float v = s * rng * 2.0f - rng;
        const float lo[3]   = {-50.f, -50.f, -5.f};
        const float span[3] = {100.f, 100.f, 8.f};
        const float rv = bev_pos[pix * 3 + coord] * span[coord] + lo[coord] + v;
        refp[pix * 24 + tid] = rv;
        rp[tid] = rv;
    } else if (tid >= 32) {
        const int j = tid - 32;
        float acc = sw_b[j];
        for (int c = 0; c < 128; ++c) acc = fmaf(qv[c], sw_w[j * 128 + c], acc);
        swraw[j] = acc;
    }
    __syncthreads();
    if (tid < 8) {
        float m = -1e30f;
#pragma unroll
        for (int l = 0; l < 4; ++l) m = fmaxf(m, swraw[tid * 4 + l]);
        float e[4], sum = 0.f;
#pragma unroll
        for (int l = 0; l < 4; ++l) { e[l] = expf(swraw[tid * 4 + l] - m); sum += e[l]; }
        const float inv = 1.0f / sum;
#pragma unroll
        for (int l = 0; l < 4; ++l) swts[pix * 32 + tid * 4 + l] = e[l] * inv;
    }

    bool keep = false;
    float gx = -2.f, gy = -2.f;
    int p = 0, n = 0;
    if (tid < 48) {
        p = tid / 6;
        n = tid - p * 6;
        const float X = rp[p * 3 + 0], Y = rp[p * 3 + 1], Z = rp[p * 3 + 2];
        const float* m = l2i + n * 16;
        const float cx = m[0] * X + m[1] * Y + m[2]  * Z + m[3];
        const float cy = m[4] * X + m[5] * Y + m[6]  * Z + m[7];
        const float cz = m[8] * X + m[9] * Y + m[10] * Z + m[11];
        const bool valid = cz > 1e-5f;
        const float zz = fmaxf(cz, 1e-5f);
        gx = valid ? (cx / zz) * (2.0f / 704.0f) - 1.0f : -2.0f;
        gy = valid ? (cy / zz) * (2.0f / 256.0f) - 1.0f : -2.0f;
        keep = (gx > -1.092f) && (gx < 1.092f) && (gy > -1.26f) && (gy < 1.26f);
    }
    const unsigned long long bm = __ballot(keep);
    if (keep) {
        const unsigned long long gmask = 0x3Full << (p * 6);
        const int slot = __popcll(bm & ((1ull << tid) - 1ull) & gmask);
        recs[(size_t)pix * 48 + p * 6 + slot] = make_float2(gx, gy);
        recn[(size_t)pix * 48 + p * 6 + slot] = n;
    }
    if (tid < 48 && (tid % 6) == 0) {
        const unsigned long long gmask = 0x3Full << (p * 6);
        cnts[pix * 8 + p] = __popcll(bm & gmask);
    }
}

// ---------------------------------------------------------------------------
// sample_k4 — round-16 v2 verbatim: no divergent tail, 1-deep register
// prefetch over r, weights in registers.
// ---------------------------------------------------------------------------
__global__ __launch_bounds__(64)
void sample_k4(const float* __restrict__ refp, const float* __restrict__ swts,
               const float2* __restrict__ recs, const int* __restrict__ recn,
               const int* __restrict__ cnts,
               const short* __restrict__ fb0,   // concatenated bf16 feats
               short* __restrict__ sfo)
{
    const int pix = blockIdx.x;
    const int tid = threadIdx.x;                   // 64
    const int c0  = tid * 2;                       // channels c0, c0+1
    __shared__ float rp[24], sw[32], tail[32];
    __shared__ float2 rec[48];
    __shared__ int rn[48];
    __shared__ int cnt[8];
    __shared__ int4   toff[192];
    __shared__ float4 twt[192];
    if (tid < 24) rp[tid] = refp[pix * 24 + tid];
    if (tid < 32) sw[tid] = swts[pix * 32 + tid];
    if (tid < 48) { rec[tid] = recs[(size_t)pix * 48 + tid]; rn[tid] = recn[(size_t)pix * 48 + tid]; }
    if (tid < 8)  cnt[tid] = cnts[pix * 8 + tid];
    __syncthreads();

    const int HL[4] = {32, 16, 8, 4};
    const int WL[4] = {88, 44, 22, 11};
    const int LB[4] = {0, 2230272, 2787840, 2927232};   // level bases (shorts)

    for (int e = tid; e < 192; e += 64) {
        const int p  = e / 24;
        const int rl = e - p * 24;
        const int r  = rl >> 2;
        const int l  = rl & 3;
        int4 off = make_int4(0, 0, 0, 0);
        float4 wt = make_float4(0.f, 0.f, 0.f, 0.f);
        if (r < cnt[p]) {
            const float gx = rec[p * 6 + r].x;
            const float gy = rec[p * 6 + r].y;
            const int   n  = rn[p * 6 + r];
            const float wl = sw[p * 4 + l];
            const int Hl = HL[l], Wl = WL[l];
            const float fx = (gx + 1.0f) * 0.5f * (float)Wl - 0.5f;
            const float fy = (gy + 1.0f) * 0.5f * (float)Hl - 0.5f;
            if (fx >= -1.0f && fx < (float)Wl && fy >= -1.0f && fy < (float)Hl) {
                const float x0f = floorf(fx), y0f = floorf(fy);
                const int x0 = (int)x0f, y0 = (int)y0f;
                const int x1 = x0 + 1, y1 = y0 + 1;
                const float wx1 = fx - x0f, wy1 = fy - y0f;
                const float wx0 = 1.0f - wx1, wy0 = 1.0f - wy1;
                const bool okx0 = (x0 >= 0), okx1 = (x1 < Wl);
                const bool oky0 = (y0 >= 0), oky1 = (y1 < Hl);
                const int xc0 = okx0 ? x0 : 0, xc1 = okx1 ? x1 : Wl - 1;
                const int yc0 = oky0 ? y0 : 0, yc1 = oky1 ? y1 : Hl - 1;
                const int base = LB[l] + n * Hl * Wl * 132;
                off.x = base + (yc0 * Wl + xc0) * 132;
                off.y = base + (yc0 * Wl + xc1) * 132;
                off.z = base + (yc1 * Wl + xc0) * 132;
                off.w = base + (yc1 * Wl + xc1) * 132;
                wt.x = (okx0 && oky0) ? wx0 * wy0 * wl : 0.f;
                wt.y = (okx1 && oky0) ? wx1 * wy0 * wl : 0.f;
                wt.z = (okx0 && oky1) ? wx0 * wy1 * wl : 0.f;
                wt.w = (okx1 && oky1) ? wx1 * wy1 * wl : 0.f;
            }
        }
        toff[e] = off;
        twt[e]  = wt;
    }
    __syncthreads();

    // load one r-batch (16 taps + 16 weights) into static registers
#define LOADB(L, W, P, R)                                                        \
    do {                                                                         \
        const int eb_ = (P) * 24 + (R) * 4;                                      \
        _Pragma("unroll")                                                        \
        for (int l = 0; l < 4; ++l) {                                            \
            const int4 offv_ = toff[eb_ + l];                                    \
            W[l] = twt[eb_ + l];                                                 \
            const int ox_ = __builtin_amdgcn_readfirstlane(offv_.x);             \
            const int oy_ = __builtin_amdgcn_readfirstlane(offv_.y);             \
            const int oz_ = __builtin_amdgcn_readfirstlane(offv_.z);             \
            const int ow_ = __builtin_amdgcn_readfirstlane(offv_.w);             \
            L[l * 4 + 0] = *(const unsigned int*)(fb0 + ox_ + c0);               \
            L[l * 4 + 1] = *(const unsigned int*)(fb0 + oy_ + c0);               \
            L[l * 4 + 2] = *(const unsigned int*)(fb0 + oz_ + c0);               \
            L[l * 4 + 3] = *(const unsigned int*)(fb0 + ow_ + c0);               \
        }                                                                        \
    } while (0)

#define FMAB(L, W)                                                               \
    do {                                                                         \
        _Pragma("unroll")                                                        \
        for (int l = 0; l < 4; ++l) {                                            \
            a0.x = fmaf(__uint_as_float(L[l * 4 + 0] << 16),          W[l].x, a0.x); \
            a0.y = fmaf(__uint_as_float(L[l * 4 + 0] & 0xFFFF0000u),  W[l].x, a0.y); \
            a1.x = fmaf(__uint_as_float(L[l * 4 + 1] << 16),          W[l].y, a1.x); \
            a1.y = fmaf(__uint_as_float(L[l * 4 + 1] & 0xFFFF0000u),  W[l].y, a1.y); \
            a2.x = fmaf(__uint_as_float(L[l * 4 + 2] << 16),          W[l].z, a2.x); \
            a2.y = fmaf(__uint_as_float(L[l * 4 + 2] & 0xFFFF0000u),  W[l].z, a2.y); \
            a3.x = fmaf(__uint_as_float(L[l * 4 + 3] << 16),          W[l].w, a3.x); \
            a3.y = fmaf(__uint_as_float(L[l * 4 + 3] & 0xFFFF0000u),  W[l].w, a3.y); \
        }                                                                        \
    } while (0)

    float2 acc[8];
#pragma unroll
    for (int p = 0; p < 8; ++p) {
        float2 a0 = {0.f, 0.f}, a1 = {0.f, 0.f}, a2 = {0.f, 0.f}, a3 = {0.f, 0.f};
        const int c = cnt[p];
        unsigned int LA[16]; float4 WA[4];
        if (c > 0) LOADB(LA, WA, p, 0);
        int r = 0;
        while (r < c) {
            unsigned int LB2[16]; float4 WB[4];
            if (r + 1 < c) LOADB(LB2, WB, p, r + 1);
            FMAB(LA, WA);
            ++r;
            if (r >= c) break;
            if (r + 1 < c) LOADB(LA, WA, p, r + 1);
            FMAB(LB2, WB);
            ++r;
        }
        acc[p].x = (a0.x + a1.x) + (a2.x + a3.x);
        acc[p].y = (a0.y + a1.y) + (a2.y + a3.y);
    }
#undef LOADB
#undef FMAB

    // tail channels 128..130 (pos3d): tap-parallel, 8 lanes per point
    {
        const int p   = tid >> 3;
        const int sub = tid & 7;
        const int c   = cnt[p];
        const int nslots = c * 16;              // (4 levels * c rows) entries x 4 taps
        float t0 = 0.f, t1 = 0.f, t2 = 0.f;
        for (int s = sub; s < nslots; s += 8) {
            const int e  = p * 24 + (s >> 2);
            const int tp = s & 3;
            const int4   offv = toff[e];
            const float4 wtv  = twt[e];
            const int   off = (tp == 0) ? offv.x : (tp == 1) ? offv.y : (tp == 2) ? offv.z : offv.w;
            const float w   = (tp == 0) ? wtv.x  : (tp == 1) ? wtv.y  : (tp == 2) ? wtv.z  : wtv.w;
            const uint2 u = *(const uint2*)(fb0 + off + 128);   // ch128..131 (8B aligned)
            t0 = fmaf(__uint_as_float(u.x << 16),         w, t0);
            t1 = fmaf(__uint_as_float(u.x & 0xFFFF0000u), w, t1);
            t2 = fmaf(__uint_as_float(u.y << 16),         w, t2);
        }
#pragma unroll
        for (int o = 4; o > 0; o >>= 1) {
            t0 += __shfl_down(t0, o, 8);
            t1 += __shfl_down(t1, o, 8);
            t2 += __shfl_down(t2, o, 8);
        }
        if (sub == 0) {
            tail[p * 4 + 0] = t0;
            tail[p * 4 + 1] = t1;
            tail[p * 4 + 2] = t2;
        }
    }
    __syncthreads();

    float2 sf1 = {0.f, 0.f}, sf2 = {0.f, 0.f};
#pragma unroll
    for (int p = 0; p < 8; ++p) {
        const float dx = rp[p * 3]     - tail[p * 4 + 0];
        const float dy = rp[p * 3 + 1] - tail[p * 4 + 1];
        const float dz = rp[p * 3 + 2] - tail[p * 4 + 2];
        const float wgt = expf(-0.1f * (dx * dx + dy * dy + dz * dz));
        sf1.x += acc[p].x;  sf1.y += acc[p].y;
        sf2.x += acc[p].x * wgt;  sf2.y += acc[p].y * wgt;
    }
    const int y = pix / WID, x = pix % WID;
    const size_t po = ((size_t)(y + 1) * 102 + (x + 1)) * 256;
    ushort2 p1; p1.x = f2bf(sf1.x); p1.y = f2bf(sf1.y);
    ushort2 p2; p2.x = f2bf(sf2.x); p2.y = f2bf(sf2.y);
    *(ushort2*)(sfo + po + c0)       = p1;
    *(ushort2*)(sfo + po + 128 + c0) = p2;
}

// ---------------------------------------------------------------------------

extern "C" void kernel_launch(void* const* d_in, const int* in_sizes, int n_in,
                              void* d_out, int out_size, void* d_ws, size_t ws_size,
                              hipStream_t stream)
{
    const float* bev_query = (const float*)d_in[0];
    const float* bev_pos   = (const float*)d_in[1];
    const float* l2i       = (const float*)d_in[2];
    const float* feat0     = (const float*)d_in[3];
    const float* feat1     = (const float*)d_in[4];
    const float* feat2     = (const float*)d_in[5];
    const float* feat3     = (const float*)d_in[6];
    const float* in_w      = (const float*)d_in[7];
    const float* in_b      = (const float*)d_in[8];
    const float* off_w     = (const float*)d_in[9];
    const float* off_b     = (const float*)d_in[10];
    const float* sw_w      = (const float*)d_in[11];
    const float* sw_b      = (const float*)d_in[12];
    const float* mid_w1    = (const float*)d_in[13];
    const float* mid_b1    = (const float*)d_in[14];
    const float* mid_w2    = (const float*)d_in[15];
    const float* mid_b2    = (const float*)d_in[16];
    const float* mid_w3    = (const float*)d_in[17];
    const float* mid_b3    = (const float*)d_in[18];
    const float* out_w     = (const float*)d_in[19];
    const float* out_b     = (const float*)d_in[20];
    float* out = (float*)d_out;

    // ---- workspace layout (lifetime-aliased) ----
    float* ws    = (float*)d_ws;
    float* qn    = ws;                       // 1,280,000
    float* refp  = qn + 1280000;             //   240,000
    float* swts  = refp + 240000;            //   320,000
    float* E     = swts + 320000;            // 6,400,000 (slab5 | fTb+recs | m1_cl | slab3/5)
    float* F     = E + 6400000;              // 1,800,000 (xcat+wcat | sf_cl | q2pad)
    float* H     = F + 1800000;              // 2,700,000 (wcat tail | m2_cl)
    short* wp_all= (short*)(H + 2700000);    // 2,441,216 sh

    float*  slab  = E;                       // conv1/conv4: 5 slabs; conv3: 3 slabs
    short*  fT0   = (short*)E;               // 2,962,080 shorts (bf16 feats, concatenated)
    float2* recs  = (float2*)(E + 1600000);  // 480,000 f2
    int*    recn  = (int*)(E + 2560000);     // 480,000
    int*    cnts  = (int*)(E + 3040000);     //  80,000
    short*  m1_cl = (short*)E;               // 5,120,000 sh [100][100][512]
    short*  xcat  = (short*)F;               // 4,153,344 sh [104][104][384] hi/lo/hi
    short*  wcat  = (short*)(F + 2100000);   // 1,228,800 sh (spills into H; dead by m2)
    short*  sf_cl = (short*)F;               // 2,663,424 sh [102][102][256]
    short*  q2pad = (short*)F;               // 1,384,448 sh [104][104][128]
    short*  m2_cl = (short*)H;               // 5,326,848 sh [102][102][512]
    short*  wp_m1 = wp_all;                  // 1,179,648
    short*  wp_m2 = wp_m1 + 1179648;         //   262,144
    short*  wp_m3 = wp_m2 + 262144;          //   589,824
    short*  wp_out= wp_m3 + 589824;          //   409,600

    const dim3 blk(256);

    // ---- weight packing (all bf16 packs in one kernel) ----
    hipLaunchKernelGGL(pack_all_bf16, dim3(14336), blk, 0, stream,
                       mid_w1, mid_w2, mid_w3, out_w, in_w, wp_all, wcat);

    // ---- 1. q1 slabs = conv5x5 split-bf16 MFMA, then qn = inorm fused ----
    hipLaunchKernelGGL(pad_cat_x, dim3(4056), blk, 0, stream, bev_query, xcat);
    hipLaunchKernelGGL((mfma_conv<384, 5, 128, 2, false, 0, 0, 5, 2>), dim3(1, 50, 20), blk, 0, stream,
                       wcat, xcat, in_b, slab, nullptr);
    hipLaunchKernelGGL(red_norm_k<5>, dim3(128), blk, 0, stream, in_b, bev_query, slab, qn);

    // ---- pad-ring zeroing (xcat/wcat dead after conv1) ----
    hipLaunchKernelGGL(zero_borders, dim3(152), blk, 0, stream, sf_cl, m2_cl);

    // ---- 2. ref points + softmax weights + projection compaction ----
    hipLaunchKernelGGL(offsw_proj, dim3(HW), dim3(64), 0, stream,
                       qn, bev_pos, off_w, off_b, sw_w, sw_b, l2i,
                       refp, swts, recs, recn, cnts);

    // ---- 3. feature transposes -> bf16 (slab5 dead) ----
    hipLaunchKernelGGL(transpose_all, dim3(11571), blk, 0, stream,
                       feat0, feat1, feat2, feat3, fT0);

    // ---- 4. sampling -> sf_cl bf16 padded(1) ----
    hipLaunchKernelGGL(sample_k4, dim3(HW), dim3(64), 0, stream,
                       refp, swts, recs, recn, cnts, fT0, sf_cl);

    // ---- 5. m1 = gelu(conv3x3 256->512), NT=2: 800 blocks ----
    hipLaunchKernelGGL((mfma_conv<256, 3, 512, 1, true, 0, 100, 1, 2>), dim3(4, 50, 4), blk, 0, stream,
                       wp_m1, sf_cl, mid_b1, nullptr, m1_cl);
    // ---- 6. m2 = gelu(conv1x1 512->512) -> padded(1), NT=2: 800 blocks ----
    hipLaunchKernelGGL((mfma_conv<512, 1, 512, 1, true, 1, 102, 1, 2>), dim3(4, 50, 4), blk, 0, stream,
                       wp_m2, m1_cl, mid_b2, nullptr, m2_cl);
    // ---- 7. q2 = inorm(qn + conv3x3 512->128), NT=2: 600 blocks ----
    hipLaunchKernelGGL((mfma_conv<512, 3, 128, 2, false, 0, 0, 3, 2>), dim3(1, 50, 12), blk, 0, stream,
                       wp_m3, m2_cl, mid_b3, slab, nullptr);
    hipLaunchKernelGGL(red_norm_k<3>, dim3(128), blk, 0, stream, mid_b3, qn, slab, qn);
    // ---- 8. q3 = inorm(qn + conv5x5 bf16), NT=2 + KSPLIT=5: 1000 blocks ----
    hipLaunchKernelGGL((pad_cl_cast<128, 2>), dim3(5411), blk, 0, stream, qn, q2pad);
    hipLaunchKernelGGL((mfma_conv<128, 5, 128, 2, false, 0, 0, 5, 2>), dim3(1, 50, 20), blk, 0, stream,
                       wp_out, q2pad, out_b, slab, nullptr);
    hipLaunchKernelGGL(red_norm_k<5>, dim3(128), blk, 0, stream, out_b, qn, slab, out);
}

// Round 13
// 493.836 us; speedup vs baseline: 1.1384x; 1.0213x over previous
//
#include <hip/hip_runtime.h>
#include <cstddef>

// ---------------------------------------------------------------------------
// SegTransformerDecoder — round 25 (= round 24 resubmitted; r24 bench was an
// infra failure "container failed twice", no kernel signal).
//  * red_norm_k: 1024-thread blocks (was 128x256 = half the chip idle on a
//    36MB streaming kernel). Per-element z-sum order unchanged; only the
//    mean/var tree regroups (~1e-7 relative) — output unchanged at tolerance.
//  * pad_cat_x merged into pack_all_bf16 as 6th grid-stride segment.
//  * Convs (depth-2 counted-vmcnt, r23 = 504.3us best) and sampler (r16 v2)
//    untouched.
// ---------------------------------------------------------------------------

#define HW   10000
#define WID  100

typedef __attribute__((ext_vector_type(8))) __bf16 bf16x8;
typedef __attribute__((ext_vector_type(4))) float f32x4;
typedef __attribute__((ext_vector_type(4))) unsigned int uint4v;

#define AS1 __attribute__((address_space(1)))
#define AS3 __attribute__((address_space(3)))

__device__ __forceinline__ float gelu_exact(float x) {
    return 0.5f * x * (1.0f + erff(x * 0.7071067811865475f));
}
__device__ __forceinline__ unsigned short f2bf(float v) {
    unsigned int b = __float_as_uint(v);
    return (unsigned short)((b + 0x7FFFu + ((b >> 16) & 1u)) >> 16);
}
__device__ __forceinline__ float bf2f(short s) {
    return __uint_as_float(((unsigned int)(unsigned short)s) << 16);
}
__device__ __forceinline__ bf16x8 load_frag(const short* p) {
    return __builtin_bit_cast(bf16x8, *(const uint4v*)p);
}

// ---------------------------------------------------------------------------
// bf16 MFMA implicit-GEMM conv, LDS-staged, BK=32, NT pixel rows.
// 3-buffer depth-2 async pipeline with counted vmcnt (r23).
// ---------------------------------------------------------------------------
template<int CIN, int KS, int COUT, int EPI, bool ACT, int OPAD, int OPW, int KSPLIT, int NT>
__global__ __launch_bounds__(256)
void mfma_conv(const short* __restrict__ wpk, const short* __restrict__ xcl,
               const float* __restrict__ bias,
               float* __restrict__ outcm, short* __restrict__ outcl)
{
    constexpr int PW = 100 + 2 * (KS / 2);
    constexpr int CHUNK = (KS + KSPLIT - 1) / KSPLIT;
    constexpr int CINB = CIN / 32;          // ic0 steps per (ky,kx)
    constexpr int BBUF = NT * 2048;         // Bs buffer stride in BYTES
    __shared__ short As[12288];             // 3 buffers x [128 oc][32 ic]
    __shared__ short Bs[NT * 3072];         // 3 buffers x [NT*32 pix][32 ic]

    const int t    = threadIdx.x;
    const int lane = t & 63;
    const int wv   = t >> 6;
    const int wr = wv >> 1;
    const int wc = wv & 1;
    const int lq = lane >> 4;
    const int ln = lane & 15;

    const int oc0 = blockIdx.x * 128;
    const int y0  = blockIdx.y * NT;
    const int zb  = blockIdx.z;
    const int bx  = (KSPLIT > 1) ? (zb & 3) : zb;
    const int ks  = (KSPLIT > 1) ? (zb >> 2) : 0;
    const int x0  = bx * 32;
    const int ky_lo = ks * CHUNK;
    const int ky_hi = (ky_lo + CHUNK < KS) ? ky_lo + CHUNK : KS;

    const int srow  = t >> 2;               // 0..63
    const int sslot = (t & 3) * 8;          // shorts (4 x 16B per 64B row)

    const int nsteps = (ky_hi - ky_lo) * KS * CINB;

    f32x4 acc[4][NT];
#pragma unroll
    for (int mt = 0; mt < 4; ++mt)
#pragma unroll
        for (int nt = 0; nt < NT; ++nt)
#pragma unroll
            for (int r = 0; r < 4; ++r) acc[mt][nt][r] = 0.f;

    // stage step s into buffer b: 3 global_load_lds per thread (A:2, B:1)
    auto stage = [&](int b, int s) {
        const int ky  = ky_lo + s / (KS * CINB);
        const int rem = s % (KS * CINB);
        const int kx  = rem / CINB;
        const int ic0 = (rem % CINB) * 32;
        const short* wsl = wpk + (size_t)((ky * KS + kx) * COUT + oc0) * CIN + ic0 + sslot;
        const short* xsl = xcl + (size_t)(ky * PW + kx) * CIN + ic0 + sslot;
#pragma unroll
        for (int i = 0; i < 2; ++i) {
            const int row = i * 64 + srow;
            const short* ga = wsl + (size_t)row * CIN;
            __builtin_amdgcn_global_load_lds(
                (const AS1 unsigned int*)ga,
                (AS3 unsigned int*)((AS3 char*)As + b * 8192 + i * 4096 + wv * 1024),
                16, 0, 0);
        }
#pragma unroll
        for (int i = 0; i < NT / 2; ++i) {
            const int np = i * 64 + srow;
            const short* gb = xsl + (size_t)((y0 + (np >> 5)) * PW + x0 + (np & 31)) * CIN;
            __builtin_amdgcn_global_load_lds(
                (const AS1 unsigned int*)gb,
                (AS3 unsigned int*)((AS3 char*)Bs + b * BBUF + i * 4096 + wv * 1024),
                16, 0, 0);
        }
    };

    stage(0, 0);
    if (nsteps > 1) stage(1, 1);

    for (int s = 0; s < nsteps; ++s) {
        const int cur = s % 3;
        if (s + 1 < nsteps) {
            asm volatile("s_waitcnt vmcnt(3)" ::: "memory");
        } else {
            asm volatile("s_waitcnt vmcnt(0)" ::: "memory");
        }
        __builtin_amdgcn_s_barrier();

        const short* ab = As + cur * 4096;
        const short* bb = Bs + cur * (NT * 1024);
        bf16x8 a[4], b[NT];
#pragma unroll
        for (int mt = 0; mt < 4; ++mt)
            a[mt] = load_frag(ab + (wr * 64 + mt * 16 + ln) * 32 + lq * 8);
#pragma unroll
        for (int nt = 0; nt < NT; ++nt)
            b[nt] = load_frag(bb + (wc * (NT * 16) + nt * 16 + ln) * 32 + lq * 8);
#pragma unroll
        for (int mt = 0; mt < 4; ++mt)
#pragma unroll
            for (int nt = 0; nt < NT; ++nt)
                acc[mt][nt] = __builtin_amdgcn_mfma_f32_16x16x32_bf16(
                    a[mt], b[nt], acc[mt][nt], 0, 0, 0);

        if (s + 2 < nsteps) stage((s + 2) % 3, s + 2);   // depth-2 prefetch
    }

#pragma unroll
    for (int mt = 0; mt < 4; ++mt) {
        const int ocr = oc0 + wr * 64 + mt * 16 + lq * 4;
        float bb[4];
        if (EPI == 1) {
            const float4 bv = *(const float4*)(bias + ocr);
            bb[0] = bv.x; bb[1] = bv.y; bb[2] = bv.z; bb[3] = bv.w;
        }
#pragma unroll
        for (int nt = 0; nt < NT; ++nt) {
            const int nl = wc * (NT * 16) + nt * 16 + ln;
            const int x = x0 + (nl & 31);
            const int y = y0 + (nl >> 5);
            if (x >= 100) continue;
            if (EPI == 1) {
                float v[4];
#pragma unroll
                for (int r = 0; r < 4; ++r) {
                    float tv = acc[mt][nt][r] + bb[r];
                    if (ACT) tv = gelu_exact(tv);
                    v[r] = tv;
                }
                ushort4 pk;
                pk.x = f2bf(v[0]); pk.y = f2bf(v[1]); pk.z = f2bf(v[2]); pk.w = f2bf(v[3]);
                *(ushort4*)(outcl + ((size_t)(y + OPAD) * OPW + (x + OPAD)) * COUT + ocr) = pk;
            } else {
                const int pix = y * WID + x;
#pragma unroll
                for (int r = 0; r < 4; ++r)
                    outcm[((size_t)ks * COUT + ocr + r) * HW + pix] = acc[mt][nt][r];
            }
        }
    }
}

// fused: out = inorm(bias + res + sum_z slab[z]); 1024-thread blocks (16 waves)
template<int NS>
__global__ __launch_bounds__(1024)
void red_norm_k(const float* __restrict__ bias, const float* __restrict__ res,
                const float* __restrict__ slab, float* __restrict__ outp)
{
    const int c = blockIdx.x, tid = threadIdx.x;
    const size_t base = (size_t)c * HW;
    const float bc = bias[c];
    float v[10];
    float s1 = 0.f, s2 = 0.f;
#pragma unroll
    for (int k = 0; k < 10; ++k) {
        const int i = tid + k * 1024;
        float x = 0.f;
        if (i < HW) {
            x = bc + res[base + i];
#pragma unroll
            for (int z = 0; z < NS; ++z) x += slab[(size_t)z * 1280000 + base + i];
            s1 += x; s2 += x * x;
        }
        v[k] = x;
    }
    __shared__ float r1[1024], r2[1024];
    r1[tid] = s1; r2[tid] = s2; __syncthreads();
    for (int o = 512; o > 0; o >>= 1) {
        if (tid < o) { r1[tid] += r1[tid + o]; r2[tid] += r2[tid + o]; }
        __syncthreads();
    }
    const float mean = r1[0] * 1e-4f;
    const float var  = fmaxf(r2[0] * 1e-4f - mean * mean, 0.f);
    const float rstd = rsqrtf(var + 1e-5f);
#pragma unroll
    for (int k = 0; k < 10; ++k) {
        const int i = tid + k * 1024;
        if (i < HW) outp[base + i] = (v[k] - mean) * rstd;
    }
}

// zero only the 1-px pad rings of sf_cl (102x102x256) and m2_cl (102x102x512)
__global__ void zero_borders(short* __restrict__ sf_cl, short* __restrict__ m2_cl)
{
    const int NSF = 404 * 32;          // 16B vectors in sf ring
    const int NM2 = 404 * 64;          // 16B vectors in m2 ring
    const uint4v z = {0u, 0u, 0u, 0u};
    for (int i = blockIdx.x * blockDim.x + threadIdx.x; i < NSF + NM2;
         i += gridDim.x * blockDim.x) {
        short* base; int pb, vc, C;
        if (i < NSF) { base = sf_cl; pb = i >> 5; vc = i & 31; C = 256; }
        else { const int j = i - NSF; base = m2_cl; pb = j >> 6; vc = j & 63; C = 512; }
        int y, x;
        if (pb < 102)      { y = 0;            x = pb; }
        else if (pb < 204) { y = 101;          x = pb - 102; }
        else if (pb < 304) { y = pb - 204 + 1; x = 0; }
        else               { y = pb - 304 + 1; x = 101; }
        *(uint4v*)(base + (size_t)(y * 102 + x) * C + vc * 8) = z;
    }
}

template<int C, int PAD>
__global__ void pad_cl_cast(const float* __restrict__ in, short* __restrict__ out)
{
    constexpr int PW = 100 + 2 * PAD;
    const int total = PW * PW * C;
    for (int i = blockIdx.x * blockDim.x + threadIdx.x; i < total; i += gridDim.x * blockDim.x) {
        const int c = i % C;
        const int p = i / C;
        const int x = p % PW - PAD;
        const int y = p / PW - PAD;
        float v = 0.f;
        if (x >= 0 && x < 100 && y >= 0 && y < 100) v = in[(size_t)c * HW + y * WID + x];
        out[i] = (short)f2bf(v);
    }
}

// Prologue fused kernel:
//  segs 1-4: mid/out weights -> bf16 packed
//  seg  5:   in_w split-cat (hi/hi/lo) -> wcat
//  seg  6:   bev_query -> x_cat bf16 padded(2) hi/lo/hi
__global__ void pack_all_bf16(const float* __restrict__ w1, const float* __restrict__ w2,
                              const float* __restrict__ w3, const float* __restrict__ w4,
                              const float* __restrict__ wc, const float* __restrict__ xq,
                              short* __restrict__ out, short* __restrict__ outc,
                              short* __restrict__ xcat)
{
    const int E0 = 1179648, E1 = E0 + 262144, E2 = E1 + 589824, E3 = E2 + 409600;
    const int E4 = E3 + 1228800;
    const int E5 = E4 + 10816 * 384;
    for (int i = blockIdx.x * blockDim.x + threadIdx.x; i < E5; i += gridDim.x * blockDim.x) {
        if (i < E3) {
            const float* w; int OC, CI, KS, j;
            if (i < E0)      { w = w1; OC = 512; CI = 256; KS = 3; j = i; }
            else if (i < E1) { w = w2; OC = 512; CI = 512; KS = 1; j = i - E0; }
            else if (i < E2) { w = w3; OC = 128; CI = 512; KS = 3; j = i - E1; }
            else             { w = w4; OC = 128; CI = 128; KS = 5; j = i - E2; }
            const int ic = j % CI;
            int t = j / CI;
            const int oc = t % OC;
            const int s = t / OC;
            const int ky = s / KS, kx = s % KS;
            out[i] = (short)f2bf(w[(((size_t)oc * CI + ic) * KS + ky) * KS + kx]);
        } else if (i < E4) {
            const int j = i - E3;
            const int c = j % 384;
            int t = j / 384;
            const int oc = t % 128;
            const int s = t / 128;
            const int ky = s / 5, kx = s % 5;
            const int sc = c & 127;
            const float v = wc[(((size_t)oc * 128 + sc) * 5 + ky) * 5 + kx];
            const unsigned short hi = f2bf(v);
            outc[j] = (c < 256) ? (short)hi : (short)f2bf(v - bf2f((short)hi));
        } else {
            const int j = i - E4;
            const int c = j % 384;
            const int p = j / 384;
            const int x = p % 104 - 2;
            const int y = p / 104 - 2;
            const int sc = c & 127;
            float v = 0.f;
            if (x >= 0 && x < 100 && y >= 0 && y < 100) v = xq[(size_t)sc * HW + y * WID + x];
            const unsigned short hi = f2bf(v);
            short o;
            if (c >= 128 && c < 256) o = (short)f2bf(v - bf2f((short)hi));
            else                     o = (short)hi;
            xcat[j] = o;
        }
    }
}

// feature transposes -> bf16 channel-last, concatenated
__global__ void transpose_all(const float* __restrict__ f0, const float* __restrict__ f1,
                              const float* __restrict__ f2, const float* __restrict__ f3,
                              short* __restrict__ out)
{
    const int O1 = 2230272, O2 = O1 + 557568, O3 = O2 + 139392, O4 = O3 + 34848;
    for (int i = blockIdx.x * blockDim.x + threadIdx.x; i < O4; i += gridDim.x * blockDim.x) {
        const float* f; int Hl, Wl, j;
        if (i < O1)      { f = f0; Hl = 32; Wl = 88; j = i; }
        else if (i < O2) { f = f1; Hl = 16; Wl = 44; j = i - O1; }
        else if (i < O3) { f = f2; Hl = 8;  Wl = 22; j = i - O2; }
        else             { f = f3; Hl = 4;  Wl = 11; j = i - O3; }
        const int c = j % 132;
        int t = j / 132;
        const int x = t % Wl; t /= Wl;
        const int y = t % Hl; t /= Hl;
        const int n = t;
        out[i] = (short)f2bf(f[(((size_t)n * 132 + c) * Hl + y) * Wl + x]);
    }
}

// offsw + projection compaction fused (unchanged)
__global__ __launch_bounds__(64)
void offsw_proj(const float* __restrict__ qn, const float* __restrict__ bev_pos,
                const float* __restrict__ off_w, const float* __restrict__ off_b,
                const float* __restrict__ sw_w, const float* __restrict__ sw_b,
                const float* __restrict__ l2i,
                float* __restrict__ refp, float* __restrict__ swts,
                float2* __restrict__ recs, int* __restrict__ recn, int* __restrict__ cnts)
{
    const int pix = blockIdx.x;
    const int tid = threadIdx.x;
    __shared__ float qv[128];
    __shared__ float swraw[32];
    __shared__ float rp[24];
    qv[tid]      = qn[(size_t)tid * HW + pix];
    qv[tid + 64] = qn[(size_t)(tid + 64) * HW + pix];
    __syncthreads();

    if (tid < 24) {
        float acc = off_b[tid];
        for (int c = 0; c < 128; ++c) acc = fmaf(qv[c], off_w[tid * 128 + c], acc);
        const float s = 1.0f / (1.0f + expf(-acc));
        const int coord = tid % 3;
        const float rng = (coord < 2) ? 0.250001f : 4.000001f;
        const float v = s * rng * 2.0f - rng;
        const float lo[3]   = {-50.f, -50.f, -5.f};
        const float span[3] = {100.f, 100.f, 8.f};
        const float rv = bev_pos[pix * 3 + coord] * span[coord] + lo[coord] + v;
        refp[pix * 24 + tid] = rv;
        rp[tid] = rv;
    } else if (tid >= 32) {
        const int j = tid - 32;
        float acc = sw_b[j];
        for (int c = 0; c < 128; ++c) acc = fmaf(qv[c], sw_w[j * 128 + c], acc);
        swraw[j] = acc;
    }
    __syncthreads();
    if (tid < 8) {
        float m = -1e30f;
#pragma unroll
        for (int l = 0; l < 4; ++l) m = fmaxf(m, swraw[tid * 4 + l]);
        float e[4], sum = 0.f;
#pragma unroll
        for (int l = 0; l < 4; ++l) { e[l] = expf(swraw[tid * 4 + l] - m); sum += e[l]; }
        const float inv = 1.0f / sum;
#pragma unroll
        for (int l = 0; l < 4; ++l) swts[pix * 32 + tid * 4 + l] = e[l] * inv;
    }

    bool keep = false;
    float gx = -2.f, gy = -2.f;
    int p = 0, n = 0;
    if (tid < 48) {
        p = tid / 6;
        n = tid - p * 6;
        const float X = rp[p * 3 + 0], Y = rp[p * 3 + 1], Z = rp[p * 3 + 2];
        const float* m = l2i + n * 16;
        const float cx = m[0] * X + m[1] * Y + m[2]  * Z + m[3];
        const float cy = m[4] * X + m[5] * Y + m[6]  * Z + m[7];
        const float cz = m[8] * X + m[9] * Y + m[10] * Z + m[11];
        const bool valid = cz > 1e-5f;
        const float zz = fmaxf(cz, 1e-5f);
        gx = valid ? (cx / zz) * (2.0f / 704.0f) - 1.0f : -2.0f;
        gy = valid ? (cy / zz) * (2.0f / 256.0f) - 1.0f : -2.0f;
        keep = (gx > -1.092f) && (gx < 1.092f) && (gy > -1.26f) && (gy < 1.26f);
    }
    const unsigned long long bm = __ballot(keep);
    if (keep) {
        const unsigned long long gmask = 0x3Full << (p * 6);
        const int slot = __popcll(bm & ((1ull << tid) - 1ull) & gmask);
        recs[(size_t)pix * 48 + p * 6 + slot] = make_float2(gx, gy);
        recn[(size_t)pix * 48 + p * 6 + slot] = n;
    }
    if (tid < 48 && (tid % 6) == 0) {
        const unsigned long long gmask = 0x3Full << (p * 6);
        cnts[pix * 8 + p] = __popcll(bm & gmask);
    }
}

// ---------------------------------------------------------------------------
// sample_k4 — round-16 v2 verbatim.
// ---------------------------------------------------------------------------
__global__ __launch_bounds__(64)
void sample_k4(const float* __restrict__ refp, const float* __restrict__ swts,
               const float2* __restrict__ recs, const int* __restrict__ recn,
               const int* __restrict__ cnts,
               const short* __restrict__ fb0,   // concatenated bf16 feats
               short* __restrict__ sfo)
{
    const int pix = blockIdx.x;
    const int tid = threadIdx.x;                   // 64
    const int c0  = tid * 2;                       // channels c0, c0+1
    __shared__ float rp[24], sw[32], tail[32];
    __shared__ float2 rec[48];
    __shared__ int rn[48];
    __shared__ int cnt[8];
    __shared__ int4   toff[192];
    __shared__ float4 twt[192];
    if (tid < 24) rp[tid] = refp[pix * 24 + tid];
    if (tid < 32) sw[tid] = swts[pix * 32 + tid];
    if (tid < 48) { rec[tid] = recs[(size_t)pix * 48 + tid]; rn[tid] = recn[(size_t)pix * 48 + tid]; }
    if (tid < 8)  cnt[tid] = cnts[pix * 8 + tid];
    __syncthreads();

    const int HL[4] = {32, 16, 8, 4};
    const int WL[4] = {88, 44, 22, 11};
    const int LB[4] = {0, 2230272, 2787840, 2927232};   // level bases (shorts)

    for (int e = tid; e < 192; e += 64) {
        const int p  = e / 24;
        const int rl = e - p * 24;
        const int r  = rl >> 2;
        const int l  = rl & 3;
        int4 off = make_int4(0, 0, 0, 0);
        float4 wt = make_float4(0.f, 0.f, 0.f, 0.f);
        if (r < cnt[p]) {
            const float gx = rec[p * 6 + r].x;
            const float gy = rec[p * 6 + r].y;
            const int   n  = rn[p * 6 + r];
            const float wl = sw[p * 4 + l];
            const int Hl = HL[l], Wl = WL[l];
            const float fx = (gx + 1.0f) * 0.5f * (float)Wl - 0.5f;
            const float fy = (gy + 1.0f) * 0.5f * (float)Hl - 0.5f;
            if (fx >= -1.0f && fx < (float)Wl && fy >= -1.0f && fy < (float)Hl) {
                const float x0f = floorf(fx), y0f = floorf(fy);
                const int x0 = (int)x0f, y0 = (int)y0f;
                const int x1 = x0 + 1, y1 = y0 + 1;
                const float wx1 = fx - x0f, wy1 = fy - y0f;
                const float wx0 = 1.0f - wx1, wy0 = 1.0f - wy1;
                const bool okx0 = (x0 >= 0), okx1 = (x1 < Wl);
                const bool oky0 = (y0 >= 0), oky1 = (y1 < Hl);
                const int xc0 = okx0 ? x0 : 0, xc1 = okx1 ? x1 : Wl - 1;
                const int yc0 = oky0 ? y0 : 0, yc1 = oky1 ? y1 : Hl - 1;
                const int base = LB[l] + n * Hl * Wl * 132;
                off.x = base + (yc0 * Wl + xc0) * 132;
                off.y = base + (yc0 * Wl + xc1) * 132;
                off.z = base + (yc1 * Wl + xc0) * 132;
                off.w = base + (yc1 * Wl + xc1) * 132;
                wt.x = (okx0 && oky0) ? wx0 * wy0 * wl : 0.f;
                wt.y = (okx1 && oky0) ? wx1 * wy0 * wl : 0.f;
                wt.z = (okx0 && oky1) ? wx0 * wy1 * wl : 0.f;
                wt.w = (okx1 && oky1) ? wx1 * wy1 * wl : 0.f;
            }
        }
        toff[e] = off;
        twt[e]  = wt;
    }
    __syncthreads();

    // load one r-batch (16 taps + 16 weights) into static registers
#define LOADB(L, W, P, R)                                                        \
    do {                                                                         \
        const int eb_ = (P) * 24 + (R) * 4;                                      \
        _Pragma("unroll")                                                        \
        for (int l = 0; l < 4; ++l) {                                            \
            const int4 offv_ = toff[eb_ + l];                                    \
            W[l] = twt[eb_ + l];                                                 \
            const int ox_ = __builtin_amdgcn_readfirstlane(offv_.x);             \
            const int oy_ = __builtin_amdgcn_readfirstlane(offv_.y);             \
            const int oz_ = __builtin_amdgcn_readfirstlane(offv_.z);             \
            const int ow_ = __builtin_amdgcn_readfirstlane(offv_.w);             \
            L[l * 4 + 0] = *(const unsigned int*)(fb0 + ox_ + c0);               \
            L[l * 4 + 1] = *(const unsigned int*)(fb0 + oy_ + c0);               \
            L[l * 4 + 2] = *(const unsigned int*)(fb0 + oz_ + c0);               \
            L[l * 4 + 3] = *(const unsigned int*)(fb0 + ow_ + c0);               \
        }                                                                        \
    } while (0)

#define FMAB(L, W)                                                               \
    do {                                                                         \
        _Pragma("unroll")                                                        \
        for (int l = 0; l < 4; ++l) {                                            \
            a0.x = fmaf(__uint_as_float(L[l * 4 + 0] << 16),          W[l].x, a0.x); \
            a0.y = fmaf(__uint_as_float(L[l * 4 + 0] & 0xFFFF0000u),  W[l].x, a0.y); \
            a1.x = fmaf(__uint_as_float(L[l * 4 + 1] << 16),          W[l].y, a1.x); \
            a1.y = fmaf(__uint_as_float(L[l * 4 + 1] & 0xFFFF0000u),  W[l].y, a1.y); \
            a2.x = fmaf(__uint_as_float(L[l * 4 + 2] << 16),          W[l].z, a2.x); \
            a2.y = fmaf(__uint_as_float(L[l * 4 + 2] & 0xFFFF0000u),  W[l].z, a2.y); \
            a3.x = fmaf(__uint_as_float(L[l * 4 + 3] << 16),          W[l].w, a3.x); \
            a3.y = fmaf(__uint_as_float(L[l * 4 + 3] & 0xFFFF0000u),  W[l].w, a3.y); \
        }                                                                        \
    } while (0)

    float2 acc[8];
#pragma unroll
    for (int p = 0; p < 8; ++p) {
        float2 a0 = {0.f, 0.f}, a1 = {0.f, 0.f}, a2 = {0.f, 0.f}, a3 = {0.f, 0.f};
        const int c = cnt[p];
        unsigned int LA[16]; float4 WA[4];
        if (c > 0) LOADB(LA, WA, p, 0);
        int r = 0;
        while (r < c) {
            unsigned int LB2[16]; float4 WB[4];
            if (r + 1 < c) LOADB(LB2, WB, p, r + 1);
            FMAB(LA, WA);
            ++r;
            if (r >= c) break;
            if (r + 1 < c) LOADB(LA, WA, p, r + 1);
            FMAB(LB2, WB);
            ++r;
        }
        acc[p].x = (a0.x + a1.x) + (a2.x + a3.x);
        acc[p].y = (a0.y + a1.y) + (a2.y + a3.y);
    }
#undef LOADB
#undef FMAB

    // tail channels 128..130 (pos3d): tap-parallel, 8 lanes per point
    {
        const int p   = tid >> 3;
        const int sub = tid & 7;
        const int c   = cnt[p];
        const int nslots = c * 16;              // (4 levels * c rows) entries x 4 taps
        float t0 = 0.f, t1 = 0.f, t2 = 0.f;
        for (int s = sub; s < nslots; s += 8) {
            const int e  = p * 24 + (s >> 2);
            const int tp = s & 3;
            const int4   offv = toff[e];
            const float4 wtv  = twt[e];
            const int   off = (tp == 0) ? offv.x : (tp == 1) ? offv.y : (tp == 2) ? offv.z : offv.w;
            const float w   = (tp == 0) ? wtv.x  : (tp == 1) ? wtv.y  : (tp == 2) ? wtv.z  : wtv.w;
            const uint2 u = *(const uint2*)(fb0 + off + 128);   // ch128..131 (8B aligned)
            t0 = fmaf(__uint_as_float(u.x << 16),         w, t0);
            t1 = fmaf(__uint_as_float(u.x & 0xFFFF0000u), w, t1);
            t2 = fmaf(__uint_as_float(u.y << 16),         w, t2);
        }
#pragma unroll
        for (int o = 4; o > 0; o >>= 1) {
            t0 += __shfl_down(t0, o, 8);
            t1 += __shfl_down(t1, o, 8);
            t2 += __shfl_down(t2, o, 8);
        }
        if (sub == 0) {
            tail[p * 4 + 0] = t0;
            tail[p * 4 + 1] = t1;
            tail[p * 4 + 2] = t2;
        }
    }
    __syncthreads();

    float2 sf1 = {0.f, 0.f}, sf2 = {0.f, 0.f};
#pragma unroll
    for (int p = 0; p < 8; ++p) {
        const float dx = rp[p * 3]     - tail[p * 4 + 0];
        const float dy = rp[p * 3 + 1] - tail[p * 4 + 1];
        const float dz = rp[p * 3 + 2] - tail[p * 4 + 2];
        const float wgt = expf(-0.1f * (dx * dx + dy * dy + dz * dz));
        sf1.x += acc[p].x;  sf1.y += acc[p].y;
        sf2.x += acc[p].x * wgt;  sf2.y += acc[p].y * wgt;
    }
    const int y = pix / WID, x = pix % WID;
    const size_t po = ((size_t)(y + 1) * 102 + (x + 1)) * 256;
    ushort2 p1; p1.x = f2bf(sf1.x); p1.y = f2bf(sf1.y);
    ushort2 p2; p2.x = f2bf(sf2.x); p2.y = f2bf(sf2.y);
    *(ushort2*)(sfo + po + c0)       = p1;
    *(ushort2*)(sfo + po + 128 + c0) = p2;
}

// ---------------------------------------------------------------------------

extern "C" void kernel_launch(void* const* d_in, const int* in_sizes, int n_in,
                              void* d_out, int out_size, void* d_ws, size_t ws_size,
                              hipStream_t stream)
{
    const float* bev_query = (const float*)d_in[0];
    const float* bev_pos   = (const float*)d_in[1];
    const float* l2i       = (const float*)d_in[2];
    const float* feat0     = (const float*)d_in[3];
    const float* feat1     = (const float*)d_in[4];
    const float* feat2     = (const float*)d_in[5];
    const float* feat3     = (const float*)d_in[6];
    const float* in_w      = (const float*)d_in[7];
    const float* in_b      = (const float*)d_in[8];
    const float* off_w     = (const float*)d_in[9];
    const float* off_b     = (const float*)d_in[10];
    const float* sw_w      = (const float*)d_in[11];
    const float* sw_b      = (const float*)d_in[12];
    const float* mid_w1    = (const float*)d_in[13];
    const float* mid_b1    = (const float*)d_in[14];
    const float* mid_w2    = (const float*)d_in[15];
    const float* mid_b2    = (const float*)d_in[16];
    const float* mid_w3    = (const float*)d_in[17];
    const float* mid_b3    = (const float*)d_in[18];
    const float* out_w     = (const float*)d_in[19];
    const float* out_b     = (const float*)d_in[20];
    float* out = (float*)d_out;

    // ---- workspace layout (lifetime-aliased) ----
    float* ws    = (float*)d_ws;
    float* qn    = ws;                       // 1,280,000
    float* refp  = qn + 1280000;             //   240,000
    float* swts  = refp + 240000;            //   320,000
    float* E     = swts + 320000;            // 6,400,000 (slab5 | fTb+recs | m1_cl | slab3/5)
    float* F     = E + 6400000;              // 1,800,000 (xcat+wcat | sf_cl | q2pad)
    float* H     = F + 1800000;              // 2,700,000 (wcat tail | m2_cl)
    short* wp_all= (short*)(H + 2700000);    // 2,441,216 sh

    float*  slab  = E;                       // conv1/conv4: 5 slabs; conv3: 3 slabs
    short*  fT0   = (short*)E;               // 2,962,080 shorts (bf16 feats, concatenated)
    float2* recs  = (float2*)(E + 1600000);  // 480,000 f2
    int*    recn  = (int*)(E + 2560000);     // 480,000
    int*    cnts  = (int*)(E + 3040000);     //  80,000
    short*  m1_cl = (short*)E;               // 5,120,000 sh [100][100][512]
    short*  xcat  = (short*)F;               // 4,153,344 sh [104][104][384] hi/lo/hi
    short*  wcat  = (short*)(F + 2100000);   // 1,228,800 sh (spills into H; dead by m2)
    short*  sf_cl = (short*)F;               // 2,663,424 sh [102][102][256]
    short*  q2pad = (short*)F;               // 1,384,448 sh [104][104][128]
    short*  m2_cl = (short*)H;               // 5,326,848 sh [102][102][512]
    short*  wp_m1 = wp_all;                  // 1,179,648
    short*  wp_m2 = wp_m1 + 1179648;         //   262,144
    short*  wp_m3 = wp_m2 + 262144;          //   589,824
    short*  wp_out= wp_m3 + 589824;          //   409,600

    const dim3 blk(256);

    // ---- prologue: all weight packs + x_cat pad in ONE kernel ----
    hipLaunchKernelGGL(pack_all_bf16, dim3(15264), blk, 0, stream,
                       mid_w1, mid_w2, mid_w3, out_w, in_w, bev_query,
                       wp_all, wcat, xcat);

    // ---- 1. q1 slabs = conv5x5 split-bf16 MFMA, then qn = inorm fused ----
    hipLaunchKernelGGL((mfma_conv<384, 5, 128, 2, false, 0, 0, 5, 2>), dim3(1, 50, 20), blk, 0, stream,
                       wcat, xcat, in_b, slab, nullptr);
    hipLaunchKernelGGL(red_norm_k<5>, dim3(128), dim3(1024), 0, stream, in_b, bev_query, slab, qn);

    // ---- pad-ring zeroing (xcat/wcat dead after conv1) ----
    hipLaunchKernelGGL(zero_borders, dim3(152), blk, 0, stream, sf_cl, m2_cl);

    // ---- 2. ref points + softmax weights + projection compaction ----
    hipLaunchKernelGGL(offsw_proj, dim3(HW), dim3(64), 0, stream,
                       qn, bev_pos, off_w, off_b, sw_w, sw_b, l2i,
                       refp, swts, recs, recn, cnts);

    // ---- 3. feature transposes -> bf16 (slab5 dead) ----
    hipLaunchKernelGGL(transpose_all, dim3(11571), blk, 0, stream,
                       feat0, feat1, feat2, feat3, fT0);

    // ---- 4. sampling -> sf_cl bf16 padded(1) ----
    hipLaunchKernelGGL(sample_k4, dim3(HW), dim3(64), 0, stream,
                       refp, swts, recs, recn, cnts, fT0, sf_cl);

    // ---- 5. m1 = gelu(conv3x3 256->512), NT=2: 800 blocks ----
    hipLaunchKernelGGL((mfma_conv<256, 3, 512, 1, true, 0, 100, 1, 2>), dim3(4, 50, 4), blk, 0, stream,
                       wp_m1, sf_cl, mid_b1, nullptr, m1_cl);
    // ---- 6. m2 = gelu(conv1x1 512->512) -> padded(1), NT=2: 800 blocks ----
    hipLaunchKernelGGL((mfma_conv<512, 1, 512, 1, true, 1, 102, 1, 2>), dim3(4, 50, 4), blk, 0, stream,
                       wp_m2, m1_cl, mid_b2, nullptr, m2_cl);
    // ---- 7. q2 = inorm(qn + conv3x3 512->128), NT=2: 600 blocks ----
    hipLaunchKernelGGL((mfma_conv<512, 3, 128, 2, false, 0, 0, 3, 2>), dim3(1, 50, 12), blk, 0, stream,
                       wp_m3, m2_cl, mid_b3, slab, nullptr);
    hipLaunchKernelGGL(red_norm_k<3>, dim3(128), dim3(1024), 0, stream, mid_b3, qn, slab, qn);
    // ---- 8. q3 = inorm(qn + conv5x5 bf16), NT=2 + KSPLIT=5: 1000 blocks ----
    hipLaunchKernelGGL((pad_cl_cast<128, 2>), dim3(5411), blk, 0, stream, qn, q2pad);
    hipLaunchKernelGGL((mfma_conv<128, 5, 128, 2, false, 0, 0, 5, 2>), dim3(1, 50, 20), blk, 0, stream,
                       wp_out, q2pad, out_b, slab, nullptr);
    hipLaunchKernelGGL(red_norm_k<5>, dim3(128), dim3(1024), 0, stream, out_b, qn, slab, out);
}

// Round 14
// 492.911 us; speedup vs baseline: 1.1405x; 1.0019x over previous
//
#include <hip/hip_runtime.h>
#include <cstddef>

// ---------------------------------------------------------------------------
// SegTransformerDecoder — round 26 (r25 + two structural eliminations).
//  * transpose_all fused into the prologue kernel (segment 7): its only
//    inputs are feat0-3, so it runs concurrently with the weight packs
//    instead of as a serial mid-pipeline dispatch. fT0 relocated to
//    H+914400 floats (disjoint from xcat tail / wcat; m2_cl overwrites H
//    only after sample_k4 consumed fT0).
//  * pad_cl_cast fused into red_norm_k<3,QPAD=1>: writes the bf16 padded
//    q2pad copy from registers (identical f2bf of identical value ->
//    bit-identical) and zeros the 816-px pad ring in the same kernel.
//  * Convs (depth-2 counted-vmcnt), sampler (r16 v2), red_norm 1024-thr,
//    zero_borders — all unchanged from r25 (493.8us best).
// ---------------------------------------------------------------------------

#define HW   10000
#define WID  100

typedef __attribute__((ext_vector_type(8))) __bf16 bf16x8;
typedef __attribute__((ext_vector_type(4))) float f32x4;
typedef __attribute__((ext_vector_type(4))) unsigned int uint4v;

#define AS1 __attribute__((address_space(1)))
#define AS3 __attribute__((address_space(3)))

__device__ __forceinline__ float gelu_exact(float x) {
    return 0.5f * x * (1.0f + erff(x * 0.7071067811865475f));
}
__device__ __forceinline__ unsigned short f2bf(float v) {
    unsigned int b = __float_as_uint(v);
    return (unsigned short)((b + 0x7FFFu + ((b >> 16) & 1u)) >> 16);
}
__device__ __forceinline__ float bf2f(short s) {
    return __uint_as_float(((unsigned int)(unsigned short)s) << 16);
}
__device__ __forceinline__ bf16x8 load_frag(const short* p) {
    return __builtin_bit_cast(bf16x8, *(const uint4v*)p);
}

// ---------------------------------------------------------------------------
// bf16 MFMA implicit-GEMM conv, LDS-staged, BK=32, NT pixel rows.
// 3-buffer depth-2 async pipeline with counted vmcnt (r23).
// ---------------------------------------------------------------------------
template<int CIN, int KS, int COUT, int EPI, bool ACT, int OPAD, int OPW, int KSPLIT, int NT>
__global__ __launch_bounds__(256)
void mfma_conv(const short* __restrict__ wpk, const short* __restrict__ xcl,
               const float* __restrict__ bias,
               float* __restrict__ outcm, short* __restrict__ outcl)
{
    constexpr int PW = 100 + 2 * (KS / 2);
    constexpr int CHUNK = (KS + KSPLIT - 1) / KSPLIT;
    constexpr int CINB = CIN / 32;          // ic0 steps per (ky,kx)
    constexpr int BBUF = NT * 2048;         // Bs buffer stride in BYTES
    __shared__ short As[12288];             // 3 buffers x [128 oc][32 ic]
    __shared__ short Bs[NT * 3072];         // 3 buffers x [NT*32 pix][32 ic]

    const int t    = threadIdx.x;
    const int lane = t & 63;
    const int wv   = t >> 6;
    const int wr = wv >> 1;
    const int wc = wv & 1;
    const int lq = lane >> 4;
    const int ln = lane & 15;

    const int oc0 = blockIdx.x * 128;
    const int y0  = blockIdx.y * NT;
    const int zb  = blockIdx.z;
    const int bx  = (KSPLIT > 1) ? (zb & 3) : zb;
    const int ks  = (KSPLIT > 1) ? (zb >> 2) : 0;
    const int x0  = bx * 32;
    const int ky_lo = ks * CHUNK;
    const int ky_hi = (ky_lo + CHUNK < KS) ? ky_lo + CHUNK : KS;

    const int srow  = t >> 2;               // 0..63
    const int sslot = (t & 3) * 8;          // shorts (4 x 16B per 64B row)

    const int nsteps = (ky_hi - ky_lo) * KS * CINB;

    f32x4 acc[4][NT];
#pragma unroll
    for (int mt = 0; mt < 4; ++mt)
#pragma unroll
        for (int nt = 0; nt < NT; ++nt)
#pragma unroll
            for (int r = 0; r < 4; ++r) acc[mt][nt][r] = 0.f;

    // stage step s into buffer b: 3 global_load_lds per thread (A:2, B:1)
    auto stage = [&](int b, int s) {
        const int ky  = ky_lo + s / (KS * CINB);
        const int rem = s % (KS * CINB);
        const int kx  = rem / CINB;
        const int ic0 = (rem % CINB) * 32;
        const short* wsl = wpk + (size_t)((ky * KS + kx) * COUT + oc0) * CIN + ic0 + sslot;
        const short* xsl = xcl + (size_t)(ky * PW + kx) * CIN + ic0 + sslot;
#pragma unroll
        for (int i = 0; i < 2; ++i) {
            const int row = i * 64 + srow;
            const short* ga = wsl + (size_t)row * CIN;
            __builtin_amdgcn_global_load_lds(
                (const AS1 unsigned int*)ga,
                (AS3 unsigned int*)((AS3 char*)As + b * 8192 + i * 4096 + wv * 1024),
                16, 0, 0);
        }
#pragma unroll
        for (int i = 0; i < NT / 2; ++i) {
            const int np = i * 64 + srow;
            const short* gb = xsl + (size_t)((y0 + (np >> 5)) * PW + x0 + (np & 31)) * CIN;
            __builtin_amdgcn_global_load_lds(
                (const AS1 unsigned int*)gb,
                (AS3 unsigned int*)((AS3 char*)Bs + b * BBUF + i * 4096 + wv * 1024),
                16, 0, 0);
        }
    };

    stage(0, 0);
    if (nsteps > 1) stage(1, 1);

    for (int s = 0; s < nsteps; ++s) {
        const int cur = s % 3;
        if (s + 1 < nsteps) {
            asm volatile("s_waitcnt vmcnt(3)" ::: "memory");
        } else {
            asm volatile("s_waitcnt vmcnt(0)" ::: "memory");
        }
        __builtin_amdgcn_s_barrier();

        const short* ab = As + cur * 4096;
        const short* bb = Bs + cur * (NT * 1024);
        bf16x8 a[4], b[NT];
#pragma unroll
        for (int mt = 0; mt < 4; ++mt)
            a[mt] = load_frag(ab + (wr * 64 + mt * 16 + ln) * 32 + lq * 8);
#pragma unroll
        for (int nt = 0; nt < NT; ++nt)
            b[nt] = load_frag(bb + (wc * (NT * 16) + nt * 16 + ln) * 32 + lq * 8);
#pragma unroll
        for (int mt = 0; mt < 4; ++mt)
#pragma unroll
            for (int nt = 0; nt < NT; ++nt)
                acc[mt][nt] = __builtin_amdgcn_mfma_f32_16x16x32_bf16(
                    a[mt], b[nt], acc[mt][nt], 0, 0, 0);

        if (s + 2 < nsteps) stage((s + 2) % 3, s + 2);   // depth-2 prefetch
    }

#pragma unroll
    for (int mt = 0; mt < 4; ++mt) {
        const int ocr = oc0 + wr * 64 + mt * 16 + lq * 4;
        float bb[4];
        if (EPI == 1) {
            const float4 bv = *(const float4*)(bias + ocr);
            bb[0] = bv.x; bb[1] = bv.y; bb[2] = bv.z; bb[3] = bv.w;
        }
#pragma unroll
        for (int nt = 0; nt < NT; ++nt) {
            const int nl = wc * (NT * 16) + nt * 16 + ln;
            const int x = x0 + (nl & 31);
            const int y = y0 + (nl >> 5);
            if (x >= 100) continue;
            if (EPI == 1) {
                float v[4];
#pragma unroll
                for (int r = 0; r < 4; ++r) {
                    float tv = acc[mt][nt][r] + bb[r];
                    if (ACT) tv = gelu_exact(tv);
                    v[r] = tv;
                }
                ushort4 pk;
                pk.x = f2bf(v[0]); pk.y = f2bf(v[1]); pk.z = f2bf(v[2]); pk.w = f2bf(v[3]);
                *(ushort4*)(outcl + ((size_t)(y + OPAD) * OPW + (x + OPAD)) * COUT + ocr) = pk;
            } else {
                const int pix = y * WID + x;
#pragma unroll
                for (int r = 0; r < 4; ++r)
                    outcm[((size_t)ks * COUT + ocr + r) * HW + pix] = acc[mt][nt][r];
            }
        }
    }
}

// fused: out = inorm(bias + res + sum_z slab[z]); 1024-thread blocks.
// QPAD: additionally write bf16 copy to qp padded(2) [104][104][128]
// (identical f2bf of identical value as the old pad_cl_cast) + zero border.
template<int NS, bool QPAD>
__global__ __launch_bounds__(1024)
void red_norm_k(const float* __restrict__ bias, const float* __restrict__ res,
                const float* __restrict__ slab, float* __restrict__ outp,
                short* __restrict__ qp)
{
    const int c = blockIdx.x, tid = threadIdx.x;
    const size_t base = (size_t)c * HW;
    const float bc = bias[c];
    float v[10];
    float s1 = 0.f, s2 = 0.f;
#pragma unroll
    for (int k = 0; k < 10; ++k) {
        const int i = tid + k * 1024;
        float x = 0.f;
        if (i < HW) {
            x = bc + res[base + i];
#pragma unroll
            for (int z = 0; z < NS; ++z) x += slab[(size_t)z * 1280000 + base + i];
            s1 += x; s2 += x * x;
        }
        v[k] = x;
    }
    __shared__ float r1[1024], r2[1024];
    r1[tid] = s1; r2[tid] = s2; __syncthreads();
    for (int o = 512; o > 0; o >>= 1) {
        if (tid < o) { r1[tid] += r1[tid + o]; r2[tid] += r2[tid + o]; }
        __syncthreads();
    }
    const float mean = r1[0] * 1e-4f;
    const float var  = fmaxf(r2[0] * 1e-4f - mean * mean, 0.f);
    const float rstd = rsqrtf(var + 1e-5f);
#pragma unroll
    for (int k = 0; k < 10; ++k) {
        const int i = tid + k * 1024;
        if (i < HW) {
            const float ov = (v[k] - mean) * rstd;
            outp[base + i] = ov;
            if (QPAD) {
                const int y = i / WID, x = i - y * WID;
                qp[(size_t)((y + 2) * 104 + (x + 2)) * 128 + c] = (short)f2bf(ov);
            }
        }
    }
    if (QPAD) {
        // zero the 816 border pixels of the 104x104 pad for this channel
        const int b = tid;
        if (b < 816) {
            int y, x;
            if (b < 208)      { y = b / 104;            x = b % 104; }
            else if (b < 416) { y = 102 + (b - 208) / 104; x = (b - 208) % 104; }
            else {
                const int j = b - 416;
                y = 2 + (j >> 2);
                const int k2 = j & 3;
                x = (k2 < 2) ? k2 : (100 + k2);
            }
            qp[(size_t)(y * 104 + x) * 128 + c] = 0;
        }
    }
}

// zero only the 1-px pad rings of sf_cl (102x102x256) and m2_cl (102x102x512)
__global__ void zero_borders(short* __restrict__ sf_cl, short* __restrict__ m2_cl)
{
    const int NSF = 404 * 32;          // 16B vectors in sf ring
    const int NM2 = 404 * 64;          // 16B vectors in m2 ring
    const uint4v z = {0u, 0u, 0u, 0u};
    for (int i = blockIdx.x * blockDim.x + threadIdx.x; i < NSF + NM2;
         i += gridDim.x * blockDim.x) {
        short* base; int pb, vc, C;
        if (i < NSF) { base = sf_cl; pb = i >> 5; vc = i & 31; C = 256; }
        else { const int j = i - NSF; base = m2_cl; pb = j >> 6; vc = j & 63; C = 512; }
        int y, x;
        if (pb < 102)      { y = 0;            x = pb; }
        else if (pb < 204) { y = 101;          x = pb - 102; }
        else if (pb < 304) { y = pb - 204 + 1; x = 0; }
        else               { y = pb - 304 + 1; x = 101; }
        *(uint4v*)(base + (size_t)(y * 102 + x) * C + vc * 8) = z;
    }
}

// Prologue fused kernel:
//  segs 1-4: mid/out weights -> bf16 packed
//  seg  5:   in_w split-cat (hi/hi/lo) -> wcat
//  seg  6:   bev_query -> x_cat bf16 padded(2) hi/lo/hi
//  seg  7:   feature transposes -> bf16 channel-last concatenated (fT0)
__global__ void pack_all_bf16(const float* __restrict__ w1, const float* __restrict__ w2,
                              const float* __restrict__ w3, const float* __restrict__ w4,
                              const float* __restrict__ wc, const float* __restrict__ xq,
                              const float* __restrict__ f0, const float* __restrict__ f1,
                              const float* __restrict__ f2, const float* __restrict__ f3,
                              short* __restrict__ out, short* __restrict__ outc,
                              short* __restrict__ xcat, short* __restrict__ fT0)
{
    const int E0 = 1179648, E1 = E0 + 262144, E2 = E1 + 589824, E3 = E2 + 409600;
    const int E4 = E3 + 1228800;
    const int E5 = E4 + 10816 * 384;
    const int O1 = 2230272, O2 = O1 + 557568, O3 = O2 + 139392, O4 = O3 + 34848;
    const int E6 = E5 + O4;
    for (int i = blockIdx.x * blockDim.x + threadIdx.x; i < E6; i += gridDim.x * blockDim.x) {
        if (i < E3) {
            const float* w; int OC, CI, KS, j;
            if (i < E0)      { w = w1; OC = 512; CI = 256; KS = 3; j = i; }
            else if (i < E1) { w = w2; OC = 512; CI = 512; KS = 1; j = i - E0; }
            else if (i < E2) { w = w3; OC = 128; CI = 512; KS = 3; j = i - E1; }
            else             { w = w4; OC = 128; CI = 128; KS = 5; j = i - E2; }
            const int ic = j % CI;
            int t = j / CI;
            const int oc = t % OC;
            const int s = t / OC;
            const int ky = s / KS, kx = s % KS;
            out[i] = (short)f2bf(w[(((size_t)oc * CI + ic) * KS + ky) * KS + kx]);
        } else if (i < E4) {
            const int j = i - E3;
            const int c = j % 384;
            int t = j / 384;
            const int oc = t % 128;
            const int s = t / 128;
            const int ky = s / 5, kx = s % 5;
            const int sc = c & 127;
            const float v = wc[(((size_t)oc * 128 + sc) * 5 + ky) * 5 + kx];
            const unsigned short hi = f2bf(v);
            outc[j] = (c < 256) ? (short)hi : (short)f2bf(v - bf2f((short)hi));
        } else if (i < E5) {
            const int j = i - E4;
            const int c = j % 384;
            const int p = j / 384;
            const int x = p % 104 - 2;
            const int y = p / 104 - 2;
            const int sc = c & 127;
            float v = 0.f;
            if (x >= 0 && x < 100 && y >= 0 && y < 100) v = xq[(size_t)sc * HW + y * WID + x];
            const unsigned short hi = f2bf(v);
            short o;
            if (c >= 128 && c < 256) o = (short)f2bf(v - bf2f((short)hi));
            else                     o = (short)hi;
            xcat[j] = o;
        } else {
            const int jj = i - E5;
            const float* f; int Hl, Wl, j;
            if (jj < O1)      { f = f0; Hl = 32; Wl = 88; j = jj; }
            else if (jj < O2) { f = f1; Hl = 16; Wl = 44; j = jj - O1; }
            else if (jj < O3) { f = f2; Hl = 8;  Wl = 22; j = jj - O2; }
            else              { f = f3; Hl = 4;  Wl = 11; j = jj - O3; }
            const int c = j % 132;
            int t = j / 132;
            const int x = t % Wl; t /= Wl;
            const int y = t % Hl; t /= Hl;
            const int n = t;
            fT0[jj] = (short)f2bf(f[(((size_t)n * 132 + c) * Hl + y) * Wl + x]);
        }
    }
}

// offsw + projection compaction fused (unchanged)
__global__ __launch_bounds__(64)
void offsw_proj(const float* __restrict__ qn, const float* __restrict__ bev_pos,
                const float* __restrict__ off_w, const float* __restrict__ off_b,
                const float* __restrict__ sw_w, const float* __restrict__ sw_b,
                const float* __restrict__ l2i,
                float* __restrict__ refp, float* __restrict__ swts,
                float2* __restrict__ recs, int* __restrict__ recn, int* __restrict__ cnts)
{
    const int pix = blockIdx.x;
    const int tid = threadIdx.x;
    __shared__ float qv[128];
    __shared__ float swraw[32];
    __shared__ float rp[24];
    qv[tid]      = qn[(size_t)tid * HW + pix];
    qv[tid + 64] = qn[(size_t)(tid + 64) * HW + pix];
    __syncthreads();

    if (tid < 24) {
        float acc = off_b[tid];
        for (int c = 0; c < 128; ++c) acc = fmaf(qv[c], off_w[tid * 128 + c], acc);
        const float s = 1.0f / (1.0f + expf(-acc));
        const int coord = tid % 3;
        const float rng = (coord < 2) ? 0.250001f : 4.000001f;
        const float v = s * rng * 2.0f - rng;
        const float lo[3]   = {-50.f, -50.f, -5.f};
        const float span[3] = {100.f, 100.f, 8.f};
        const float rv = bev_pos[pix * 3 + coord] * span[coord] + lo[coord] + v;
        refp[pix * 24 + tid] = rv;
        rp[tid] = rv;
    } else if (tid >= 32) {
        const int j = tid - 32;
        float acc = sw_b[j];
        for (int c = 0; c < 128; ++c) acc = fmaf(qv[c], sw_w[j * 128 + c], acc);
        swraw[j] = acc;
    }
    __syncthreads();
    if (tid < 8) {
        float m = -1e30f;
#pragma unroll
        for (int l = 0; l < 4; ++l) m = fmaxf(m, swraw[tid * 4 + l]);
        float e[4], sum = 0.f;
#pragma unroll
        for (int l = 0; l < 4; ++l) { e[l] = expf(swraw[tid * 4 + l] - m); sum += e[l]; }
        const float inv = 1.0f / sum;
#pragma unroll
        for (int l = 0; l < 4; ++l) swts[pix * 32 + tid * 4 + l] = e[l] * inv;
    }

    bool keep = false;
    float gx = -2.f, gy = -2.f;
    int p = 0, n = 0;
    if (tid < 48) {
        p = tid / 6;
        n = tid - p * 6;
        const float X = rp[p * 3 + 0], Y = rp[p * 3 + 1], Z = rp[p * 3 + 2];
        const float* m = l2i + n * 16;
        const float cx = m[0] * X + m[1] * Y + m[2]  * Z + m[3];
        const float cy = m[4] * X + m[5] * Y + m[6]  * Z + m[7];
        const float cz = m[8] * X + m[9] * Y + m[10] * Z + m[11];
        const bool valid = cz > 1e-5f;
        const float zz = fmaxf(cz, 1e-5f);
        gx = valid ? (cx / zz) * (2.0f / 704.0f) - 1.0f : -2.0f;
        gy = valid ? (cy / zz) * (2.0f / 256.0f) - 1.0f : -2.0f;
        keep = (gx > -1.092f) && (gx < 1.092f) && (gy > -1.26f) && (gy < 1.26f);
    }
    const unsigned long long bm = __ballot(keep);
    if (keep) {
        const unsigned long long gmask = 0x3Full << (p * 6);
        const int slot = __popcll(bm & ((1ull << tid) - 1ull) & gmask);
        recs[(size_t)pix * 48 + p * 6 + slot] = make_float2(gx, gy);
        recn[(size_t)pix * 48 + p * 6 + slot] = n;
    }
    if (tid < 48 && (tid % 6) == 0) {
        const unsigned long long gmask = 0x3Full << (p * 6);
        cnts[pix * 8 + p] = __popcll(bm & gmask);
    }
}

// ---------------------------------------------------------------------------
// sample_k4 — round-16 v2 verbatim.
// ---------------------------------------------------------------------------
__global__ __launch_bounds__(64)
void sample_k4(const float* __restrict__ refp, const float* __restrict__ swts,
               const float2* __restrict__ recs, const int* __restrict__ recn,
               const int* __restrict__ cnts,
               const short* __restrict__ fb0,   // concatenated bf16 feats
               short* __restrict__ sfo)
{
    const int pix = blockIdx.x;
    const int tid = threadIdx.x;                   // 64
    const int c0  = tid * 2;                       // channels c0, c0+1
    __shared__ float rp[24], sw[32], tail[32];
    __shared__ float2 rec[48];
    __shared__ int rn[48];
    __shared__ int cnt[8];
    __shared__ int4   toff[192];
    __shared__ float4 twt[192];
    if (tid < 24) rp[tid] = refp[pix * 24 + tid];
    if (tid < 32) sw[tid] = swts[pix * 32 + tid];
    if (tid < 48) { rec[tid] = recs[(size_t)pix * 48 + tid]; rn[tid] = recn[(size_t)pix * 48 + tid]; }
    if (tid < 8)  cnt[tid] = cnts[pix * 8 + tid];
    __syncthreads();

    const int HL[4] = {32, 16, 8, 4};
    const int WL[4] = {88, 44, 22, 11};
    const int LB[4] = {0, 2230272, 2787840, 2927232};   // level bases (shorts)

    for (int e = tid; e < 192; e += 64) {
        const int p  = e / 24;
        const int rl = e - p * 24;
        const int r  = rl >> 2;
        const int l  = rl & 3;
        int4 off = make_int4(0, 0, 0, 0);
        float4 wt = make_float4(0.f, 0.f, 0.f, 0.f);
        if (r < cnt[p]) {
            const float gx = rec[p * 6 + r].x;
            const float gy = rec[p * 6 + r].y;
            const int   n  = rn[p * 6 + r];
            const float wl = sw[p * 4 + l];
            const int Hl = HL[l], Wl = WL[l];
            const float fx = (gx + 1.0f) * 0.5f * (float)Wl - 0.5f;
            const float fy = (gy + 1.0f) * 0.5f * (float)Hl - 0.5f;
            if (fx >= -1.0f && fx < (float)Wl && fy >= -1.0f && fy < (float)Hl) {
                const float x0f = floorf(fx), y0f = floorf(fy);
                const int x0 = (int)x0f, y0 = (int)y0f;
                const int x1 = x0 + 1, y1 = y0 + 1;
                const float wx1 = fx - x0f, wy1 = fy - y0f;
                const float wx0 = 1.0f - wx1, wy0 = 1.0f - wy1;
                const bool okx0 = (x0 >= 0), okx1 = (x1 < Wl);
                const bool oky0 = (y0 >= 0), oky1 = (y1 < Hl);
                const int xc0 = okx0 ? x0 : 0, xc1 = okx1 ? x1 : Wl - 1;
                const int yc0 = oky0 ? y0 : 0, yc1 = oky1 ? y1 : Hl - 1;
                const int base = LB[l] + n * Hl * Wl * 132;
                off.x = base + (yc0 * Wl + xc0) * 132;
                off.y = base + (yc0 * Wl + xc1) * 132;
                off.z = base + (yc1 * Wl + xc0) * 132;
                off.w = base + (yc1 * Wl + xc1) * 132;
                wt.x = (okx0 && oky0) ? wx0 * wy0 * wl : 0.f;
                wt.y = (okx1 && oky0) ? wx1 * wy0 * wl : 0.f;
                wt.z = (okx0 && oky1) ? wx0 * wy1 * wl : 0.f;
                wt.w = (okx1 && oky1) ? wx1 * wy1 * wl : 0.f;
            }
        }
        toff[e] = off;
        twt[e]  = wt;
    }
    __syncthreads();

    // load one r-batch (16 taps + 16 weights) into static registers
#define LOADB(L, W, P, R)                                                        \
    do {                                                                         \
        const int eb_ = (P) * 24 + (R) * 4;                                      \
        _Pragma("unroll")                                                        \
        for (int l = 0; l < 4; ++l) {                                            \
            const int4 offv_ = toff[eb_ + l];                                    \
            W[l] = twt[eb_ + l];                                                 \
            const int ox_ = __builtin_amdgcn_readfirstlane(offv_.x);             \
            const int oy_ = __builtin_amdgcn_readfirstlane(offv_.y);             \
            const int oz_ = __builtin_amdgcn_readfirstlane(offv_.z);             \
            const int ow_ = __builtin_amdgcn_readfirstlane(offv_.w);             \
            L[l * 4 + 0] = *(const unsigned int*)(fb0 + ox_ + c0);               \
            L[l * 4 + 1] = *(const unsigned int*)(fb0 + oy_ + c0);               \
            L[l * 4 + 2] = *(const unsigned int*)(fb0 + oz_ + c0);               \
            L[l * 4 + 3] = *(const unsigned int*)(fb0 + ow_ + c0);               \
        }                                                                        \
    } while (0)

#define FMAB(L, W)                                                               \
    do {                                                                         \
        _Pragma("unroll")                                                        \
        for (int l = 0; l < 4; ++l) {                                            \
            a0.x = fmaf(__uint_as_float(L[l * 4 + 0] << 16),          W[l].x, a0.x); \
            a0.y = fmaf(__uint_as_float(L[l * 4 + 0] & 0xFFFF0000u),  W[l].x, a0.y); \
            a1.x = fmaf(__uint_as_float(L[l * 4 + 1] << 16),          W[l].y, a1.x); \
            a1.y = fmaf(__uint_as_float(L[l * 4 + 1] & 0xFFFF0000u),  W[l].y, a1.y); \
            a2.x = fmaf(__uint_as_float(L[l * 4 + 2] << 16),          W[l].z, a2.x); \
            a2.y = fmaf(__uint_as_float(L[l * 4 + 2] & 0xFFFF0000u),  W[l].z, a2.y); \
            a3.x = fmaf(__uint_as_float(L[l * 4 + 3] << 16),          W[l].w, a3.x); \
            a3.y = fmaf(__uint_as_float(L[l * 4 + 3] & 0xFFFF0000u),  W[l].w, a3.y); \
        }                                                                        \
    } while (0)

    float2 acc[8];
#pragma unroll
    for (int p = 0; p < 8; ++p) {
        float2 a0 = {0.f, 0.f}, a1 = {0.f, 0.f}, a2 = {0.f, 0.f}, a3 = {0.f, 0.f};
        const int c = cnt[p];
        unsigned int LA[16]; float4 WA[4];
        if (c > 0) LOADB(LA, WA, p, 0);
        int r = 0;
        while (r < c) {
            unsigned int LB2[16]; float4 WB[4];
            if (r + 1 < c) LOADB(LB2, WB, p, r + 1);
            FMAB(LA, WA);
            ++r;
            if (r >= c) break;
            if (r + 1 < c) LOADB(LA, WA, p, r + 1);
            FMAB(LB2, WB);
            ++r;
        }
        acc[p].x = (a0.x + a1.x) + (a2.x + a3.x);
        acc[p].y = (a0.y + a1.y) + (a2.y + a3.y);
    }
#undef LOADB
#undef FMAB

    // tail channels 128..130 (pos3d): tap-parallel, 8 lanes per point
    {
        const int p   = tid >> 3;
        const int sub = tid & 7;
        const int c   = cnt[p];
        const int nslots = c * 16;              // (4 levels * c rows) entries x 4 taps
        float t0 = 0.f, t1 = 0.f, t2 = 0.f;
        for (int s = sub; s < nslots; s += 8) {
            const int e  = p * 24 + (s >> 2);
            const int tp = s & 3;
            const int4   offv = toff[e];
            const float4 wtv  = twt[e];
            const int   off = (tp == 0) ? offv.x : (tp == 1) ? offv.y : (tp == 2) ? offv.z : offv.w;
            const float w   = (tp == 0) ? wtv.x  : (tp == 1) ? wtv.y  : (tp == 2) ? wtv.z  : wtv.w;
            const uint2 u = *(const uint2*)(fb0 + off + 128);   // ch128..131 (8B aligned)
            t0 = fmaf(__uint_as_float(u.x << 16),         w, t0);
            t1 = fmaf(__uint_as_float(u.x & 0xFFFF0000u), w, t1);
            t2 = fmaf(__uint_as_float(u.y << 16),         w, t2);
        }
#pragma unroll
        for (int o = 4; o > 0; o >>= 1) {
            t0 += __shfl_down(t0, o, 8);
            t1 += __shfl_down(t1, o, 8);
            t2 += __shfl_down(t2, o, 8);
        }
        if (sub == 0) {
            tail[p * 4 + 0] = t0;
            tail[p * 4 + 1] = t1;
            tail[p * 4 + 2] = t2;
        }
    }
    __syncthreads();

    float2 sf1 = {0.f, 0.f}, sf2 = {0.f, 0.f};
#pragma unroll
    for (int p = 0; p < 8; ++p) {
        const float dx = rp[p * 3]     - tail[p * 4 + 0];
        const float dy = rp[p * 3 + 1] - tail[p * 4 + 1];
        const float dz = rp[p * 3 + 2] - tail[p * 4 + 2];
        const float wgt = expf(-0.1f * (dx * dx + dy * dy + dz * dz));
        sf1.x += acc[p].x;  sf1.y += acc[p].y;
        sf2.x += acc[p].x * wgt;  sf2.y += acc[p].y * wgt;
    }
    const int y = pix / WID, x = pix % WID;
    const size_t po = ((size_t)(y + 1) * 102 + (x + 1)) * 256;
    ushort2 p1; p1.x = f2bf(sf1.x); p1.y = f2bf(sf1.y);
    ushort2 p2; p2.x = f2bf(sf2.x); p2.y = f2bf(sf2.y);
    *(ushort2*)(sfo + po + c0)       = p1;
    *(ushort2*)(sfo + po + 128 + c0) = p2;
}

// ---------------------------------------------------------------------------

extern "C" void kernel_launch(void* const* d_in, const int* in_sizes, int n_in,
                              void* d_out, int out_size, void* d_ws, size_t ws_size,
                              hipStream_t stream)
{
    const float* bev_query = (const float*)d_in[0];
    const float* bev_pos   = (const float*)d_in[1];
    const float* l2i       = (const float*)d_in[2];
    const float* feat0     = (const float*)d_in[3];
    const float* feat1     = (const float*)d_in[4];
    const float* feat2     = (const float*)d_in[5];
    const float* feat3     = (const float*)d_in[6];
    const float* in_w      = (const float*)d_in[7];
    const float* in_b      = (const float*)d_in[8];
    const float* off_w     = (const float*)d_in[9];
    const float* off_b     = (const float*)d_in[10];
    const float* sw_w      = (const float*)d_in[11];
    const float* sw_b      = (const float*)d_in[12];
    const float* mid_w1    = (const float*)d_in[13];
    const float* mid_b1    = (const float*)d_in[14];
    const float* mid_w2    = (const float*)d_in[15];
    const float* mid_b2    = (const float*)d_in[16];
    const float* mid_w3    = (const float*)d_in[17];
    const float* mid_b3    = (const float*)d_in[18];
    const float* out_w     = (const float*)d_in[19];
    const float* out_b     = (const float*)d_in[20];
    float* out = (float*)d_out;

    // ---- workspace layout (lifetime-aliased) ----
    float* ws    = (float*)d_ws;
    float* qn    = ws;                       // 1,280,000
    float* refp  = qn + 1280000;             //   240,000
    float* swts  = refp + 240000;            //   320,000
    float* E     = swts + 320000;            // 6,400,000 (slab5 | recs | m1_cl | slab3/5)
    float* F     = E + 6400000;              // 1,800,000 (xcat head | sf_cl | q2pad)
    float* H     = F + 1800000;              // 2,700,000 (xcat tail | wcat | fT0 | m2_cl)
    short* wp_all= (short*)(H + 2700000);    // 2,441,216 sh

    float*  slab  = E;                       // conv1/conv4: 5 slabs; conv3: 3 slabs
    float2* recs  = (float2*)(E + 1600000);  // 480,000 f2
    int*    recn  = (int*)(E + 2560000);     // 480,000
    int*    cnts  = (int*)(E + 3040000);     //  80,000
    short*  m1_cl = (short*)E;               // 5,120,000 sh [100][100][512]
    short*  xcat  = (short*)F;               // 4,153,344 sh (ends H+276,672 f)
    short*  wcat  = (short*)(F + 2100000);   // 1,228,800 sh = H[300000..914400] f
    short*  fT0   = (short*)(H + 914400);    // 2,962,080 sh (ends H+2,395,440 f)
    short*  sf_cl = (short*)F;               // 2,663,424 sh [102][102][256]
    short*  q2pad = (short*)F;               // 1,384,448 sh [104][104][128]
    short*  m2_cl = (short*)H;               // 5,326,848 sh [102][102][512]
    short*  wp_m1 = wp_all;                  // 1,179,648
    short*  wp_m2 = wp_m1 + 1179648;         //   262,144
    short*  wp_m3 = wp_m2 + 262144;          //   589,824
    short*  wp_out= wp_m3 + 589824;          //   409,600

    const dim3 blk(256);

    // ---- prologue: weight packs + x_cat pad + feature transposes, ONE kernel ----
    hipLaunchKernelGGL(pack_all_bf16, dim3(16384), blk, 0, stream,
                       mid_w1, mid_w2, mid_w3, out_w, in_w, bev_query,
                       feat0, feat1, feat2, feat3,
                       wp_all, wcat, xcat, fT0);

    // ---- 1. q1 slabs = conv5x5 split-bf16 MFMA, then qn = inorm fused ----
    hipLaunchKernelGGL((mfma_conv<384, 5, 128, 2, false, 0, 0, 5, 2>), dim3(1, 50, 20), blk, 0, stream,
                       wcat, xcat, in_b, slab, nullptr);
    hipLaunchKernelGGL((red_norm_k<5, false>), dim3(128), dim3(1024), 0, stream,
                       in_b, bev_query, slab, qn, nullptr);

    // ---- pad-ring zeroing (xcat head dead after conv1; sf_cl/m2_cl rings) ----
    hipLaunchKernelGGL(zero_borders, dim3(152), blk, 0, stream, sf_cl, m2_cl);

    // ---- 2. ref points + softmax weights + projection compaction ----
    hipLaunchKernelGGL(offsw_proj, dim3(HW), dim3(64), 0, stream,
                       qn, bev_pos, off_w, off_b, sw_w, sw_b, l2i,
                       refp, swts, recs, recn, cnts);

    // ---- 3. sampling -> sf_cl bf16 padded(1) (fT0 in H, staged by prologue) ----
    hipLaunchKernelGGL(sample_k4, dim3(HW), dim3(64), 0, stream,
                       refp, swts, recs, recn, cnts, fT0, sf_cl);

    // ---- 4. m1 = gelu(conv3x3 256->512), NT=2: 800 blocks ----
    hipLaunchKernelGGL((mfma_conv<256, 3, 512, 1, true, 0, 100, 1, 2>), dim3(4, 50, 4), blk, 0, stream,
                       wp_m1, sf_cl, mid_b1, nullptr, m1_cl);
    // ---- 5. m2 = gelu(conv1x1 512->512) -> padded(1), NT=2: 800 blocks ----
    hipLaunchKernelGGL((mfma_conv<512, 1, 512, 1, true, 1, 102, 1, 2>), dim3(4, 50, 4), blk, 0, stream,
                       wp_m2, m1_cl, mid_b2, nullptr, m2_cl);
    // ---- 6. q2 = inorm(qn + conv3x3 512->128) + fused q2pad bf16 ----
    hipLaunchKernelGGL((mfma_conv<512, 3, 128, 2, false, 0, 0, 3, 2>), dim3(1, 50, 12), blk, 0, stream,
                       wp_m3, m2_cl, mid_b3, slab, nullptr);
    hipLaunchKernelGGL((red_norm_k<3, true>), dim3(128), dim3(1024), 0, stream,
                       mid_b3, qn, slab, qn, q2pad);
    // ---- 7. q3 = inorm(qn + conv5x5 bf16), NT=2 + KSPLIT=5: 1000 blocks ----
    hipLaunchKernelGGL((mfma_conv<128, 5, 128, 2, false, 0, 0, 5, 2>), dim3(1, 50, 20), blk, 0, stream,
                       wp_out, q2pad, out_b, slab, nullptr);
    hipLaunchKernelGGL((red_norm_k<5, false>), dim3(128), dim3(1024), 0, stream,
                       out_b, qn, slab, out, nullptr);
}